// Round 3
// baseline (6877.830 us; speedup 1.0000x reference)
//
#include <hip/hip_runtime.h>
#include <hip/hip_bf16.h>
#include <math.h>

// ---- problem constants ----
#define B_     64
#define NTOK   197
#define NPATCH 196
#define D768   768
#define NL     12
#define NH     12
#define MFF    3072
#define NCLS   1000
#define ROWS   (B_ * NTOK)      // 12608
#define PROWS  (B_ * NPATCH)    // 12544
#define ROWS_PAD 12800          // 50 * 256 (BM=256 M-tile padding)

typedef unsigned short ushort;
typedef __bf16 bf16x8 __attribute__((ext_vector_type(8)));
typedef float  f32x4  __attribute__((ext_vector_type(4)));

__device__ __forceinline__ ushort f2b(float f) {
  __hip_bfloat16 h = __float2bfloat16(f);
  return *reinterpret_cast<ushort*>(&h);
}

__device__ __forceinline__ void gload16(const ushort* g, ushort* lds) {
  __builtin_amdgcn_global_load_lds((const __attribute__((address_space(1))) void*)g,
                                   (__attribute__((address_space(3))) void*)lds, 16, 0, 0);
}

// ---------------- block-wide mean/rstd over 768 elems (256 threads) ----------------
__device__ __forceinline__ void block_mean_rstd(float s, float sq, float& mean, float& rstd) {
#pragma unroll
  for (int off = 32; off; off >>= 1) { s += __shfl_xor(s, off); sq += __shfl_xor(sq, off); }
  __shared__ float ss[4], ssq[4];
  int w = threadIdx.x >> 6;
  if ((threadIdx.x & 63) == 0) { ss[w] = s; ssq[w] = sq; }
  __syncthreads();
  s  = ss[0] + ss[1] + ss[2] + ss[3];
  sq = ssq[0] + ssq[1] + ssq[2] + ssq[3];
  mean = s * (1.0f / 768.0f);
  float var = sq * (1.0f / 768.0f) - mean * mean;
  rstd = rsqrtf(var + 1e-5f);
}

// ---------------- LN over rows of 768 (fp32 in, bf16 out) ----------------
__global__ __launch_bounds__(256) void ln_rows_b(const float* __restrict__ in, long in_stride,
                                                 const float* __restrict__ g,
                                                 const float* __restrict__ bta,
                                                 ushort* __restrict__ out) {
  const float* xr = in + (size_t)blockIdx.x * in_stride;
  int t = threadIdx.x;
  float v0 = xr[t], v1 = xr[t + 256], v2 = xr[t + 512];
  float mean, rstd;
  block_mean_rstd(v0 + v1 + v2, v0 * v0 + v1 * v1 + v2 * v2, mean, rstd);
  ushort* o = out + (size_t)blockIdx.x * 768;
  o[t]       = f2b((v0 - mean) * rstd * g[t]       + bta[t]);
  o[t + 256] = f2b((v1 - mean) * rstd * g[t + 256] + bta[t + 256]);
  o[t + 512] = f2b((v2 - mean) * rstd * g[t + 512] + bta[t + 512]);
}

// ---------------- patch extraction + LN1 (bf16 out) ----------------
__global__ __launch_bounds__(256) void patch_ln1(const float* __restrict__ img,
                                                 const float* __restrict__ g,
                                                 const float* __restrict__ bta,
                                                 ushort* __restrict__ xp) {
  int pidx = blockIdx.x;                 // b*196 + ph*14 + pw
  int b = pidx / NPATCH, hw = pidx % NPATCH;
  int ph = hw / 14, pw = hw % 14;
  int t = threadIdx.x;
  float v[3];
#pragma unroll
  for (int u = 0; u < 3; ++u) {
    int k = t + u * 256;                  // feature index (p1*16+p2)*3 + c
    int c = k % 3, p2 = (k / 3) & 15, p1 = k / 48;
    v[u] = img[(((size_t)b * 3 + c) * 224 + ph * 16 + p1) * 224 + pw * 16 + p2];
  }
  float mean, rstd;
  block_mean_rstd(v[0] + v[1] + v[2], v[0] * v[0] + v[1] * v[1] + v[2] * v[2], mean, rstd);
  ushort* o = xp + (size_t)pidx * 768;
#pragma unroll
  for (int u = 0; u < 3; ++u) { int k = t + u * 256; o[k] = f2b((v[u] - mean) * rstd * g[k] + bta[k]); }
}

// ---------------- LN2 + pos_emb, scatter into x at token 1+i (fp32) ----------------
__global__ __launch_bounds__(256) void ln2_pos(const float* __restrict__ xe,
                                               const float* __restrict__ g,
                                               const float* __restrict__ bta,
                                               const float* __restrict__ pos,
                                               float* __restrict__ x) {
  int pidx = blockIdx.x;
  int b = pidx / NPATCH, i = pidx % NPATCH;
  const float* xr = xe + (size_t)pidx * 768;
  int t = threadIdx.x;
  float v0 = xr[t], v1 = xr[t + 256], v2 = xr[t + 512];
  float mean, rstd;
  block_mean_rstd(v0 + v1 + v2, v0 * v0 + v1 * v1 + v2 * v2, mean, rstd);
  const float* p = pos + (size_t)(1 + i) * 768;
  float* o = x + ((size_t)b * NTOK + 1 + i) * 768;
  o[t]       = (v0 - mean) * rstd * g[t]       + bta[t]       + p[t];
  o[t + 256] = (v1 - mean) * rstd * g[t + 256] + bta[t + 256] + p[t + 256];
  o[t + 512] = (v2 - mean) * rstd * g[t + 512] + bta[t + 512] + p[t + 512];
}

// ---------------- cls token + pos_emb[0] ----------------
__global__ __launch_bounds__(256) void cls_init(const float* __restrict__ cls_tok,
                                                const float* __restrict__ pos,
                                                float* __restrict__ x) {
  int b = blockIdx.x, t = threadIdx.x;
  float* o = x + (size_t)b * NTOK * 768;
#pragma unroll
  for (int u = 0; u < 3; ++u) { int k = t + u * 256; o[k] = cls_tok[k] + pos[k]; }
}

// ---------------- cast + transpose: W fp32 [K][N] -> Wt bf16 [N][K] ----------------
__global__ __launch_bounds__(256) void transpose_cast(const float* __restrict__ W,
                                                      ushort* __restrict__ Wt,
                                                      int K, int N) {
  __shared__ float t[32][33];
  int n0 = blockIdx.x * 32, k0 = blockIdx.y * 32;
  int tx = threadIdx.x, ty = threadIdx.y;   // 32 x 8
#pragma unroll
  for (int u = 0; u < 32; u += 8) {
    int n = n0 + tx;
    t[ty + u][tx] = (n < N) ? W[(size_t)(k0 + ty + u) * N + n] : 0.f;
  }
  __syncthreads();
#pragma unroll
  for (int u = 0; u < 32; u += 8) {
    int n = n0 + ty + u;
    if (n < N) Wt[(size_t)n * K + k0 + tx] = f2b(t[tx][ty + u]);
  }
}

// ================= 8-phase 256-col MFMA GEMM: C = A @ Bt^T =================
// A [M][K] bf16, Bt [N][K] bf16. K % 64 == 0, N tile = 256, M tile = BM (256/128).
// 512 threads = 8 waves (2 Mrow x 4 Ncol). Wave output: (BM/2) x 64.
// LDS: k-split halves, each ksub block [rows][32] contiguous; st_16x32 swizzle
// (elem-group g ^= ((row>>3)&1)<<1) applied on the pre-swizzled global source
// (global_load_lds writes linearly) and on the ds_read side (rule #21).
// Schedule per K-tile (BK=64): 4 phases (ksub, m-half); phase = {ds_read frags,
// stage one half of tile t+1 into buf^1, BAR, setprio+MFMAx(4*MH)+setprio, BAR}.
// Counted waits: vmcnt(4|3) before the closing barriers of phases 1 and 3 only
// (2 halves stay in flight); vmcnt(0) only entering the last K-tile.
template<int BM>
__global__ __launch_bounds__(512, 2) void gemm8p(const ushort* __restrict__ A,
                                                 const ushort* __restrict__ Bt,
                                                 const float* __restrict__ bias,
                                                 const float* __restrict__ resid,
                                                 void* __restrict__ Cv,
                                                 int M, int N, int K, int ep, int obf) {
  constexpr int MFR = BM / 32;   // m-frags per wave (8 or 4)
  constexpr int MH  = MFR / 2;   // m-frags per half
  constexpr int ACH = BM * 4;    // 16B chunks per A ksub-half
  extern __shared__ ushort smem[];
  ushort* sA = smem;                    // [2buf][2ksub][BM][32]
  ushort* sB = smem + 4 * BM * 32;      // [2buf][2ksub][256][32]

  const int tid = threadIdx.x;
  const int w = tid >> 6, l = tid & 63;
  const int fr = l & 15, fc = l >> 4;
  const int wrow = w >> 2, wcol = w & 3;

  // bijective XCD-aware block swizzle (m204 variant)
  const int ntx = gridDim.x;
  const int nwg = ntx * gridDim.y;
  const int orig = blockIdx.y * ntx + blockIdx.x;
  const int q = nwg >> 3, r = nwg & 7, xcd = orig & 7, idx = orig >> 3;
  const int wg = (xcd < r ? xcd * (q + 1) : r * (q + 1) + (xcd - r) * q) + idx;
  const int row0 = (wg / ntx) * BM;
  const int col0 = (wg % ntx) * 256;

  const int NT = K >> 6;

  auto stA = [&](int u, int s) {
    ushort* dst = sA + (size_t)(((u & 1) * 2 + s) * BM) * 32;
    int kb = u * 64 + s * 32;
#pragma unroll
    for (int c0 = 0; c0 < ACH; c0 += 512) {
      int c = c0 + tid;
      int row = c >> 2, g = c & 3;
      int gs = g ^ (((row >> 3) & 1) << 1);
      gload16(A + (size_t)(row0 + row) * K + kb + gs * 8, dst + c * 8);
    }
  };
  auto stB = [&](int u, int s) {
    ushort* dst = sB + (size_t)(((u & 1) * 2 + s) * 256) * 32;
    int kb = u * 64 + s * 32;
#pragma unroll
    for (int c0 = 0; c0 < 1024; c0 += 512) {
      int c = c0 + tid;
      int row = c >> 2, g = c & 3;
      int gs = g ^ (((row >> 3) & 1) << 1);
      gload16(Bt + (size_t)(col0 + row) * K + kb + gs * 8, dst + c * 8);
    }
  };
  auto rdA = [&](int buf, int s, int mf) -> bf16x8 {
    int row = wrow * (BM / 2) + mf * 16 + fr;
    int g = fc ^ (((row >> 3) & 1) << 1);
    return *(const bf16x8*)(sA + (size_t)((buf * 2 + s) * BM + row) * 32 + g * 8);
  };
  auto rdB = [&](int buf, int s, int nf) -> bf16x8 {
    int row = wcol * 64 + nf * 16 + fr;
    int g = fc ^ (((row >> 3) & 1) << 1);
    return *(const bf16x8*)(sB + (size_t)((buf * 2 + s) * 256 + row) * 32 + g * 8);
  };

#define VM_W() do { if constexpr (BM == 256) asm volatile("s_waitcnt vmcnt(4)" ::: "memory"); \
                    else                     asm volatile("s_waitcnt vmcnt(3)" ::: "memory"); } while (0)
#define BARS() do { __builtin_amdgcn_sched_barrier(0); __builtin_amdgcn_s_barrier(); \
                    __builtin_amdgcn_sched_barrier(0); } while (0)

  f32x4 acc[MFR][4] = {};

  // prologue: stage tile 0 in consumption order
  stA(0, 0); stB(0, 0); stA(0, 1); stB(0, 1);
  VM_W();
  BARS();

  for (int t = 0; t < NT; ++t) {
    const int buf = t & 1;
    const bool more = (t + 1 < NT);
    bf16x8 aF[MH], bF[4];

    // ---- phase 0: (ksub 0, m-half 0) ----
#pragma unroll
    for (int mf = 0; mf < MH; ++mf) aF[mf] = rdA(buf, 0, mf);
#pragma unroll
    for (int nf = 0; nf < 4; ++nf) bF[nf] = rdB(buf, 0, nf);
    if (more) stA(t + 1, 0);
    BARS();
    __builtin_amdgcn_s_setprio(1);
#pragma unroll
    for (int mf = 0; mf < MH; ++mf)
#pragma unroll
      for (int nf = 0; nf < 4; ++nf)
        acc[mf][nf] = __builtin_amdgcn_mfma_f32_16x16x32_bf16(aF[mf], bF[nf], acc[mf][nf], 0, 0, 0);
    __builtin_amdgcn_s_setprio(0);
    BARS();

    // ---- phase 1: (ksub 0, m-half 1) ----
#pragma unroll
    for (int mf = 0; mf < MH; ++mf) aF[mf] = rdA(buf, 0, MH + mf);
    if (more) stB(t + 1, 0);
    BARS();
    __builtin_amdgcn_s_setprio(1);
#pragma unroll
    for (int mf = 0; mf < MH; ++mf)
#pragma unroll
      for (int nf = 0; nf < 4; ++nf)
        acc[MH + mf][nf] = __builtin_amdgcn_mfma_f32_16x16x32_bf16(aF[mf], bF[nf], acc[MH + mf][nf], 0, 0, 0);
    __builtin_amdgcn_s_setprio(0);
    if (t == NT - 1) asm volatile("s_waitcnt vmcnt(0)" ::: "memory");
    else VM_W();
    BARS();

    // ---- phase 2: (ksub 1, m-half 0) ----
#pragma unroll
    for (int mf = 0; mf < MH; ++mf) aF[mf] = rdA(buf, 1, mf);
#pragma unroll
    for (int nf = 0; nf < 4; ++nf) bF[nf] = rdB(buf, 1, nf);
    if (more) stA(t + 1, 1);
    BARS();
    __builtin_amdgcn_s_setprio(1);
#pragma unroll
    for (int mf = 0; mf < MH; ++mf)
#pragma unroll
      for (int nf = 0; nf < 4; ++nf)
        acc[mf][nf] = __builtin_amdgcn_mfma_f32_16x16x32_bf16(aF[mf], bF[nf], acc[mf][nf], 0, 0, 0);
    __builtin_amdgcn_s_setprio(0);
    BARS();

    // ---- phase 3: (ksub 1, m-half 1) ----
#pragma unroll
    for (int mf = 0; mf < MH; ++mf) aF[mf] = rdA(buf, 1, MH + mf);
    if (more) stB(t + 1, 1);
    BARS();
    __builtin_amdgcn_s_setprio(1);
#pragma unroll
    for (int mf = 0; mf < MH; ++mf)
#pragma unroll
      for (int nf = 0; nf < 4; ++nf)
        acc[MH + mf][nf] = __builtin_amdgcn_mfma_f32_16x16x32_bf16(aF[mf], bF[nf], acc[MH + mf][nf], 0, 0, 0);
    __builtin_amdgcn_s_setprio(0);
    if (more) { VM_W(); }
    BARS();
  }
#undef VM_W
#undef BARS

  // ---- epilogue ----
#pragma unroll
  for (int nf = 0; nf < 4; ++nf) {
    int col = col0 + wcol * 64 + nf * 16 + fr;
    if (col >= N) continue;
    float bv = bias ? bias[col] : 0.f;
#pragma unroll
    for (int mf = 0; mf < MFR; ++mf) {
#pragma unroll
      for (int rr = 0; rr < 4; ++rr) {
        int row = row0 + wrow * (BM / 2) + mf * 16 + fc * 4 + rr;
        if (row >= M) continue;
        float v = acc[mf][nf][rr] + bv;
        if (ep) v = 0.5f * v * (1.0f + erff(v * 0.70710678118654752f));
        if (resid) v += resid[(size_t)row * N + col];
        if (obf) ((ushort*)Cv)[(size_t)row * N + col] = f2b(v);
        else     ((float*)Cv)[(size_t)row * N + col]  = v;
      }
    }
  }
}

// ---------------- old 128x128 bf16 MFMA GEMM (kept for the head) ----------------
template<int EP, int RESID, int OBF>
__global__ __launch_bounds__(256) void gemm_bt(const ushort* __restrict__ A,
                                               const ushort* __restrict__ Bt,
                                               const float* __restrict__ bias,
                                               const float* __restrict__ resid,
                                               void* __restrict__ C,
                                               int M, int N, int K) {
  __shared__ ushort As[128 * 32];
  __shared__ ushort Bs[128 * 32];
  int tid = threadIdx.x;
  int w = tid >> 6, l = tid & 63;
  int fr = l & 15, fc = l >> 4;
  int row0 = blockIdx.y * 128, col0 = blockIdx.x * 128;
  int wr = (w >> 1) * 64, wc = (w & 1) * 64;

  int srow0 = w * 32 + (l >> 2);
  int srow1 = srow0 + 16;
  int sc0 = (((l & 3) ^ ((srow0 >> 1) & 3)) << 3);
  int sc1 = (((l & 3) ^ ((srow1 >> 1) & 3)) << 3);
  const ushort* ga0 = A  + (size_t)(row0 + srow0) * K + sc0;
  const ushort* ga1 = A  + (size_t)(row0 + srow1) * K + sc1;
  const ushort* gb0 = Bt + (size_t)(col0 + srow0) * K + sc0;
  const ushort* gb1 = Bt + (size_t)(col0 + srow1) * K + sc1;

  int idxA[4], idxB[4];
#pragma unroll
  for (int m = 0; m < 4; ++m) {
    int r = wr + m * 16 + fr;
    idxA[m] = r * 32 + ((fc ^ ((r >> 1) & 3)) << 3);
  }
#pragma unroll
  for (int n = 0; n < 4; ++n) {
    int r = wc + n * 16 + fr;
    idxB[n] = r * 32 + ((fc ^ ((r >> 1) & 3)) << 3);
  }

  f32x4 acc[4][4] = {};

  for (int k0 = 0; k0 < K; k0 += 32) {
    gload16(ga0 + k0, &As[w * 1024]);
    gload16(ga1 + k0, &As[w * 1024 + 512]);
    gload16(gb0 + k0, &Bs[w * 1024]);
    gload16(gb1 + k0, &Bs[w * 1024 + 512]);
    __syncthreads();
    bf16x8 af[4], bf[4];
#pragma unroll
    for (int m = 0; m < 4; ++m) af[m] = *(const bf16x8*)(As + idxA[m]);
#pragma unroll
    for (int n = 0; n < 4; ++n) bf[n] = *(const bf16x8*)(Bs + idxB[n]);
#pragma unroll
    for (int m = 0; m < 4; ++m)
#pragma unroll
      for (int n = 0; n < 4; ++n)
        acc[m][n] = __builtin_amdgcn_mfma_f32_16x16x32_bf16(af[m], bf[n], acc[m][n], 0, 0, 0);
    __syncthreads();
  }

#pragma unroll
  for (int n = 0; n < 4; ++n) {
    int col = col0 + wc + n * 16 + fr;
    if (col >= N) continue;
    float bv = bias ? bias[col] : 0.f;
#pragma unroll
    for (int m = 0; m < 4; ++m) {
#pragma unroll
      for (int r = 0; r < 4; ++r) {
        int row = row0 + wr + m * 16 + fc * 4 + r;
        if (row >= M) continue;
        float v = acc[m][n][r] + bv;
        if (EP == 1) v = 0.5f * v * (1.0f + erff(v * 0.70710678118654752f));
        if (RESID) v += resid[(size_t)row * N + col];
        if (OBF) ((ushort*)C)[(size_t)row * N + col] = f2b(v);
        else     ((float*)C)[(size_t)row * N + col]  = v;
      }
    }
  }
}

// ---------------- MFMA flash attention ----------------
__global__ __launch_bounds__(256) void attn_mfma(const ushort* __restrict__ qkv,
                                                 ushort* __restrict__ aout) {
  int bid = blockIdx.x;
  int qt = bid & 3;
  int h  = (bid >> 2) % NH;
  int b  = (bid >> 2) / NH;
  int tid = threadIdx.x, w = tid >> 6, l = tid & 63;
  int fr = l & 15, fc = l >> 4;

  __shared__ ushort Vt[64 * 64];        // swizzled V^T tile [d][key]
  __shared__ ushort Pl[4 * 16 * 64];    // per-wave P [qrow][key], swizzled

  const size_t brow = (size_t)b * NTOK;
  int q0 = qt * 64 + w * 16;

  bf16x8 qf[2];
  {
    const ushort* qp = qkv + (brow + q0 + fr) * 2304 + h * 64 + fc * 8;
    qf[0] = *(const bf16x8*)qp;
    qf[1] = *(const bf16x8*)(qp + 32);
  }
  float rs[4] = {0.f, 0.f, 0.f, 0.f};
  f32x4 oc[4] = {};

  for (int kt = 0; kt < 4; ++kt) {
    __syncthreads();
    {
      int key = tid >> 2, d0 = (tid & 3) * 16;
      int j = kt * 64 + key;
      bool valid = j < NTOK;
      const ushort* vp = qkv + (brow + j) * 2304 + 1536 + h * 64 + d0;
      ushort vbuf[16];
      if (valid) {
        *(bf16x8*)(vbuf)     = *(const bf16x8*)vp;
        *(bf16x8*)(vbuf + 8) = *(const bf16x8*)(vp + 8);
      } else {
#pragma unroll
        for (int i = 0; i < 16; ++i) vbuf[i] = 0;
      }
#pragma unroll
      for (int i = 0; i < 16; ++i) {
        int d = d0 + i;
        int byte = d * 128 + ((((key >> 3)) ^ (d & 7)) << 4) + (key & 7) * 2;
        Vt[byte >> 1] = vbuf[i];
      }
    }
    f32x4 sc[4];
#pragma unroll
    for (int n = 0; n < 4; ++n) {
      f32x4 z = {};
      const ushort* kp = qkv + (brow + kt * 64 + n * 16 + fr) * 2304 + 768 + h * 64 + fc * 8;
      bf16x8 k0 = *(const bf16x8*)kp;
      bf16x8 k1 = *(const bf16x8*)(kp + 32);
      z = __builtin_amdgcn_mfma_f32_16x16x32_bf16(qf[0], k0, z, 0, 0, 0);
      z = __builtin_amdgcn_mfma_f32_16x16x32_bf16(qf[1], k1, z, 0, 0, 0);
      sc[n] = z;
    }
    float part[4] = {0.f, 0.f, 0.f, 0.f};
#pragma unroll
    for (int n = 0; n < 4; ++n) {
      int j = kt * 64 + n * 16 + fr;
      bool jv = j < NTOK;
#pragma unroll
      for (int r = 0; r < 4; ++r) {
        float e = jv ? __expf(sc[n][r] * 0.125f) : 0.f;
        part[r] += e;
        int row = fc * 4 + r, col = n * 16 + fr;
        int byte = row * 128 + (((col >> 3) ^ (row & 7)) << 4) + (col & 7) * 2;
        Pl[w * 1024 + (byte >> 1)] = f2b(e);
      }
    }
#pragma unroll
    for (int r = 0; r < 4; ++r) {
      float p = part[r];
      p += __shfl_xor(p, 1); p += __shfl_xor(p, 2);
      p += __shfl_xor(p, 4); p += __shfl_xor(p, 8);
      rs[r] += p;
    }
    __syncthreads();
#pragma unroll
    for (int ks = 0; ks < 2; ++ks) {
      int prow = fr;
      int pbyte = prow * 128 + (((ks * 4 + fc) ^ (prow & 7)) << 4);
      bf16x8 pf = *(const bf16x8*)(Pl + w * 1024 + (pbyte >> 1));
#pragma unroll
      for (int n = 0; n < 4; ++n) {
        int d = n * 16 + fr;
        int vb = d * 128 + (((ks * 4 + fc) ^ (d & 7)) << 4);
        bf16x8 vf = *(const bf16x8*)(Vt + (vb >> 1));
        oc[n] = __builtin_amdgcn_mfma_f32_16x16x32_bf16(pf, vf, oc[n], 0, 0, 0);
      }
    }
  }
#pragma unroll
  for (int n = 0; n < 4; ++n) {
#pragma unroll
    for (int r = 0; r < 4; ++r) {
      int q = q0 + fc * 4 + r;
      if (q < NTOK) {
        float v = oc[n][r] / (rs[r] + 1e-8f);
        aout[(brow + q) * 768 + h * 64 + n * 16 + fr] = f2b(v);
      }
    }
  }
}

// ---------------- host launch ----------------
extern "C" void kernel_launch(void* const* d_in, const int* in_sizes, int n_in,
                              void* d_out, int out_size, void* d_ws, size_t ws_size,
                              hipStream_t stream) {
  const float* img       = (const float*)d_in[0];
  const float* p_ln1_g   = (const float*)d_in[1];
  const float* p_ln1_b   = (const float*)d_in[2];
  const float* patch_w   = (const float*)d_in[3];
  const float* patch_b   = (const float*)d_in[4];
  const float* p_ln2_g   = (const float*)d_in[5];
  const float* p_ln2_b   = (const float*)d_in[6];
  const float* pos_emb   = (const float*)d_in[7];
  const float* cls_tok   = (const float*)d_in[8];
  const float* attn_ln_g = (const float*)d_in[9];
  const float* attn_ln_b = (const float*)d_in[10];
  const float* w_qkv     = (const float*)d_in[11];
  const float* w_out     = (const float*)d_in[12];
  const float* b_out     = (const float*)d_in[13];
  const float* ff_ln_g   = (const float*)d_in[14];
  const float* ff_ln_b   = (const float*)d_in[15];
  const float* ff_w1     = (const float*)d_in[16];
  const float* ff_b1     = (const float*)d_in[17];
  const float* ff_w2     = (const float*)d_in[18];
  const float* ff_b2     = (const float*)d_in[19];
  const float* fin_ln_g  = (const float*)d_in[20];
  const float* fin_ln_b  = (const float*)d_in[21];
  const float* head_w    = (const float*)d_in[22];
  const float* head_b    = (const float*)d_in[23];
  float* out = (float*)d_out;

  // opt-in to >64KB dynamic LDS (idempotent; errors ignored)
  (void)hipFuncSetAttribute((const void*)gemm8p<256>,
                            hipFuncAttributeMaxDynamicSharedMemorySize, 131072);
  (void)hipFuncSetAttribute((const void*)gemm8p<128>,
                            hipFuncAttributeMaxDynamicSharedMemorySize, 98304);

  // ---- workspace carve ----
  char* p = (char*)d_ws;
  auto alloc = [&](size_t bytes) { char* r = p; p += (bytes + 255) & ~(size_t)255; return r; };
  float*  x      = (float*) alloc((size_t)ROWS_PAD * 768 * 4);
  ushort* xnb    = (ushort*)alloc((size_t)ROWS_PAD * 768 * 2);
  ushort* qkvb   = (ushort*)alloc((size_t)ROWS_PAD * 2304 * 2);
  ushort* aoutb  = (ushort*)alloc((size_t)ROWS_PAD * 768 * 2);
  ushort* wtq    = (ushort*)alloc((size_t)2304 * 768 * 2);
  ushort* wto    = (ushort*)alloc((size_t)768 * 768 * 2);
  ushort* wt1    = (ushort*)alloc((size_t)3072 * 768 * 2);
  ushort* wt2    = (ushort*)alloc((size_t)768 * 3072 * 2);
  ushort* pwt    = (ushort*)alloc((size_t)768 * 768 * 2);
  ushort* hwt    = (ushort*)alloc((size_t)1024 * 768 * 2);
  ushort* xclsb  = (ushort*)alloc((size_t)128 * 768 * 2);
  ushort* hidb   = qkvb;                 // [ROWS_PAD][3072] aliases qkvb+aoutb
  ushort* xpb    = xnb;                  // patch LN1 out (12544 rows)
  float*  xe     = (float*)qkvb;         // patch GEMM out fp32 (pre-loop only)

  dim3 blk(256), blk8(512), tblk(32, 8);

  // ---- patch embedding ----
  transpose_cast<<<dim3(24, 24), tblk, 0, stream>>>(patch_w, pwt, 768, 768);
  transpose_cast<<<dim3(32, 24), tblk, 0, stream>>>(head_w, hwt, 768, 1000);
  patch_ln1<<<PROWS, blk, 0, stream>>>(img, p_ln1_g, p_ln1_b, xpb);
  gemm8p<128><<<dim3(3, 98), blk8, 98304, stream>>>(xpb, pwt, patch_b, nullptr, xe,
                                                    PROWS, 768, 768, 0, 0);
  ln2_pos<<<PROWS, blk, 0, stream>>>(xe, p_ln2_g, p_ln2_b, pos_emb, x);
  cls_init<<<B_, blk, 0, stream>>>(cls_tok, pos_emb, x);

  for (int l = 0; l < NL; ++l) {
    transpose_cast<<<dim3(72, 24), tblk, 0, stream>>>(w_qkv + (size_t)l * 768 * 2304, wtq, 768, 2304);
    transpose_cast<<<dim3(24, 24), tblk, 0, stream>>>(w_out + (size_t)l * 768 * 768,  wto, 768, 768);
    transpose_cast<<<dim3(96, 24), tblk, 0, stream>>>(ff_w1 + (size_t)l * 768 * MFF,  wt1, 768, MFF);
    transpose_cast<<<dim3(24, 96), tblk, 0, stream>>>(ff_w2 + (size_t)l * MFF * 768,  wt2, MFF, 768);

    ln_rows_b<<<ROWS, blk, 0, stream>>>(x, 768, attn_ln_g + (size_t)l * 768,
                                        attn_ln_b + (size_t)l * 768, xnb);
    gemm8p<256><<<dim3(9, 50), blk8, 131072, stream>>>(xnb, wtq, nullptr, nullptr, qkvb,
                                                       ROWS, 2304, 768, 0, 1);
    attn_mfma<<<B_ * NH * 4, blk, 0, stream>>>(qkvb, aoutb);
    gemm8p<128><<<dim3(3, 99), blk8, 98304, stream>>>(aoutb, wto, b_out + (size_t)l * 768,
                                                      x, x, ROWS, 768, 768, 0, 0);
    ln_rows_b<<<ROWS, blk, 0, stream>>>(x, 768, ff_ln_g + (size_t)l * 768,
                                        ff_ln_b + (size_t)l * 768, xnb);
    gemm8p<256><<<dim3(12, 50), blk8, 131072, stream>>>(xnb, wt1, ff_b1 + (size_t)l * MFF,
                                                        nullptr, hidb, ROWS, MFF, 768, 1, 1);
    gemm8p<128><<<dim3(3, 99), blk8, 98304, stream>>>(hidb, wt2, ff_b2 + (size_t)l * 768,
                                                      x, x, ROWS, 768, MFF, 0, 0);
  }

  // ---- final LN (cls rows) + head ----
  ln_rows_b<<<B_, blk, 0, stream>>>(x, (long)NTOK * 768, fin_ln_g, fin_ln_b, xclsb);
  gemm_bt<0, 0, 0><<<dim3(8, 1), blk, 0, stream>>>(xclsb, hwt, head_b, nullptr, out,
                                                   B_, NCLS, 768);
}

// Round 4
// 6749.154 us; speedup vs baseline: 1.0191x; 1.0191x over previous
//
#include <hip/hip_runtime.h>
#include <hip/hip_bf16.h>
#include <math.h>

// ---- problem constants ----
#define B_     64
#define NTOK   197
#define NPATCH 196
#define D768   768
#define NL     12
#define NH     12
#define MFF    3072
#define NCLS   1000
#define ROWS   (B_ * NTOK)      // 12608
#define PROWS  (B_ * NPATCH)    // 12544
#define ROWS_PAD 12800          // 50 * 256

typedef unsigned short ushort;
typedef __bf16 bf16x8 __attribute__((ext_vector_type(8)));
typedef float  f32x4  __attribute__((ext_vector_type(4)));

__device__ __forceinline__ ushort f2b(float f) {
  __hip_bfloat16 h = __float2bfloat16(f);
  return *reinterpret_cast<ushort*>(&h);
}

__device__ __forceinline__ void gload16(const ushort* g, ushort* lds) {
  __builtin_amdgcn_global_load_lds((const __attribute__((address_space(1))) void*)g,
                                   (__attribute__((address_space(3))) void*)lds, 16, 0, 0);
}

// ---------------- block-wide mean/rstd over 768 elems (256 threads) ----------------
__device__ __forceinline__ void block_mean_rstd(float s, float sq, float& mean, float& rstd) {
#pragma unroll
  for (int off = 32; off; off >>= 1) { s += __shfl_xor(s, off); sq += __shfl_xor(sq, off); }
  __shared__ float ss[4], ssq[4];
  int w = threadIdx.x >> 6;
  if ((threadIdx.x & 63) == 0) { ss[w] = s; ssq[w] = sq; }
  __syncthreads();
  s  = ss[0] + ss[1] + ss[2] + ss[3];
  sq = ssq[0] + ssq[1] + ssq[2] + ssq[3];
  mean = s * (1.0f / 768.0f);
  float var = sq * (1.0f / 768.0f) - mean * mean;
  rstd = rsqrtf(var + 1e-5f);
}

// ---------------- LN over rows of 768 (fp32 in, bf16 out) ----------------
__global__ __launch_bounds__(256) void ln_rows_b(const float* __restrict__ in, long in_stride,
                                                 const float* __restrict__ g,
                                                 const float* __restrict__ bta,
                                                 ushort* __restrict__ out) {
  const float* xr = in + (size_t)blockIdx.x * in_stride;
  int t = threadIdx.x;
  float v0 = xr[t], v1 = xr[t + 256], v2 = xr[t + 512];
  float mean, rstd;
  block_mean_rstd(v0 + v1 + v2, v0 * v0 + v1 * v1 + v2 * v2, mean, rstd);
  ushort* o = out + (size_t)blockIdx.x * 768;
  o[t]       = f2b((v0 - mean) * rstd * g[t]       + bta[t]);
  o[t + 256] = f2b((v1 - mean) * rstd * g[t + 256] + bta[t + 256]);
  o[t + 512] = f2b((v2 - mean) * rstd * g[t + 512] + bta[t + 512]);
}

// ---------------- patch extraction + LN1 (bf16 out) ----------------
__global__ __launch_bounds__(256) void patch_ln1(const float* __restrict__ img,
                                                 const float* __restrict__ g,
                                                 const float* __restrict__ bta,
                                                 ushort* __restrict__ xp) {
  int pidx = blockIdx.x;                 // b*196 + ph*14 + pw
  int b = pidx / NPATCH, hw = pidx % NPATCH;
  int ph = hw / 14, pw = hw % 14;
  int t = threadIdx.x;
  float v[3];
#pragma unroll
  for (int u = 0; u < 3; ++u) {
    int k = t + u * 256;                  // feature index (p1*16+p2)*3 + c
    int c = k % 3, p2 = (k / 3) & 15, p1 = k / 48;
    v[u] = img[(((size_t)b * 3 + c) * 224 + ph * 16 + p1) * 224 + pw * 16 + p2];
  }
  float mean, rstd;
  block_mean_rstd(v[0] + v[1] + v[2], v[0] * v[0] + v[1] * v[1] + v[2] * v[2], mean, rstd);
  ushort* o = xp + (size_t)pidx * 768;
#pragma unroll
  for (int u = 0; u < 3; ++u) { int k = t + u * 256; o[k] = f2b((v[u] - mean) * rstd * g[k] + bta[k]); }
}

// ---------------- LN2 + pos_emb, scatter into x at token 1+i (fp32) ----------------
__global__ __launch_bounds__(256) void ln2_pos(const float* __restrict__ xe,
                                               const float* __restrict__ g,
                                               const float* __restrict__ bta,
                                               const float* __restrict__ pos,
                                               float* __restrict__ x) {
  int pidx = blockIdx.x;
  int b = pidx / NPATCH, i = pidx % NPATCH;
  const float* xr = xe + (size_t)pidx * 768;
  int t = threadIdx.x;
  float v0 = xr[t], v1 = xr[t + 256], v2 = xr[t + 512];
  float mean, rstd;
  block_mean_rstd(v0 + v1 + v2, v0 * v0 + v1 * v1 + v2 * v2, mean, rstd);
  const float* p = pos + (size_t)(1 + i) * 768;
  float* o = x + ((size_t)b * NTOK + 1 + i) * 768;
  o[t]       = (v0 - mean) * rstd * g[t]       + bta[t]       + p[t];
  o[t + 256] = (v1 - mean) * rstd * g[t + 256] + bta[t + 256] + p[t + 256];
  o[t + 512] = (v2 - mean) * rstd * g[t + 512] + bta[t + 512] + p[t + 512];
}

// ---------------- cls token + pos_emb[0] ----------------
__global__ __launch_bounds__(256) void cls_init(const float* __restrict__ cls_tok,
                                                const float* __restrict__ pos,
                                                float* __restrict__ x) {
  int b = blockIdx.x, t = threadIdx.x;
  float* o = x + (size_t)b * NTOK * 768;
#pragma unroll
  for (int u = 0; u < 3; ++u) { int k = t + u * 256; o[k] = cls_tok[k] + pos[k]; }
}

// ---------------- cast + transpose: W fp32 [K][N] -> Wt bf16 [N][K] (bounds-checked) ----------------
__global__ __launch_bounds__(256) void transpose_cast(const float* __restrict__ W,
                                                      ushort* __restrict__ Wt,
                                                      int K, int N) {
  __shared__ float t[32][33];
  int n0 = blockIdx.x * 32, k0 = blockIdx.y * 32;
  int tx = threadIdx.x, ty = threadIdx.y;   // 32 x 8
#pragma unroll
  for (int u = 0; u < 32; u += 8) {
    int n = n0 + tx;
    t[ty + u][tx] = (n < N) ? W[(size_t)(k0 + ty + u) * N + n] : 0.f;
  }
  __syncthreads();
#pragma unroll
  for (int u = 0; u < 32; u += 8) {
    int n = n0 + ty + u;
    if (n < N) Wt[(size_t)n * K + k0 + tx] = f2b(t[tx][ty + u]);
  }
}

// ---------------- merged per-layer transposes (all dims %32==0, no bounds) ----------------
__global__ __launch_bounds__(256) void transpose4(const float* __restrict__ wq,
                                                  const float* __restrict__ wo,
                                                  const float* __restrict__ w1,
                                                  const float* __restrict__ w2,
                                                  ushort* __restrict__ tq,
                                                  ushort* __restrict__ to,
                                                  ushort* __restrict__ t1,
                                                  ushort* __restrict__ t2) {
  int bid = blockIdx.x;
  const float* W; ushort* Wt; int K, N, xt;
  if (bid < 1728)      {             W = wq; Wt = tq; K = 768;  N = 2304; xt = 72; }
  else if (bid < 2304) { bid -= 1728; W = wo; Wt = to; K = 768;  N = 768;  xt = 24; }
  else if (bid < 4608) { bid -= 2304; W = w1; Wt = t1; K = 768;  N = 3072; xt = 96; }
  else                 { bid -= 4608; W = w2; Wt = t2; K = 3072; N = 768;  xt = 24; }
  int n0 = (bid % xt) * 32, k0 = (bid / xt) * 32;
  __shared__ float t[32][33];
  int tx = threadIdx.x, ty = threadIdx.y;   // 32 x 8
#pragma unroll
  for (int u = 0; u < 32; u += 8)
    t[ty + u][tx] = W[(size_t)(k0 + ty + u) * N + n0 + tx];
  __syncthreads();
#pragma unroll
  for (int u = 0; u < 32; u += 8)
    Wt[(size_t)(n0 + ty + u) * K + k0 + tx] = f2b(t[tx][ty + u]);
}

// ================= 8-phase 256-col MFMA GEMM: C = A @ Bt^T =================
// A [M][K] bf16, Bt [N][K] bf16. K % 64 == 0. N tile = 256, M tile = BM.
// 512 threads = 8 waves (2 Mrow x 4 Ncol). st_16x32-style swizzle both-sides.
// Counted vmcnt: never drains to 0 in the main loop (except entering last tile).
// NO sched_barrier(0) except after data-guard barriers (m141 lesson).
template<int BM>
__global__ __launch_bounds__(512, 2) void gemm8p(const ushort* __restrict__ A,
                                                 const ushort* __restrict__ Bt,
                                                 const float* __restrict__ bias,
                                                 const float* __restrict__ resid,
                                                 void* __restrict__ Cv,
                                                 int M, int N, int K, int ep, int obf) {
  constexpr int MFR = BM / 32;   // m-frags per wave
  constexpr int MH  = MFR / 2;
  extern __shared__ ushort smem[];
  ushort* sA = smem;                    // [2buf][2ksub][BM][32]
  ushort* sB = smem + 4 * BM * 32;      // [2buf][2ksub][256][32]

  const int tid = threadIdx.x;
  const int w = tid >> 6, l = tid & 63;
  const int fr = l & 15, fc = l >> 4;
  const int wrow = w >> 2, wcol = w & 3;

  // bijective XCD-aware block swizzle (m204 variant)
  const int ntx = gridDim.x;
  const int nwg = ntx * gridDim.y;
  const int orig = blockIdx.y * ntx + blockIdx.x;
  const int q = nwg >> 3, r = nwg & 7, xcd = orig & 7, idx = orig >> 3;
  const int wg = (xcd < r ? xcd * (q + 1) : r * (q + 1) + (xcd - r) * q) + idx;
  const int row0 = (wg / ntx) * BM;
  const int col0 = (wg % ntx) * 256;

  const int NT = K >> 6;

  // ---- staging: precomputed per-thread global bases (offset per phase = kb elems) ----
  const int cA0 = tid, cA1 = tid + 512;            // chunk ids
  const int ar0 = cA0 >> 2, ag0 = (cA0 & 3) ^ (((ar0 >> 3) & 1) << 1);
  const int ar1 = (cA1 >> 2) & (BM - 1), ag1 = (cA1 & 3) ^ (((ar1 >> 3) & 1) << 1);
  const ushort* pA0 = A + (size_t)(row0 + ar0) * K + ag0 * 8;
  const ushort* pA1 = A + (size_t)(row0 + ar1) * K + ag1 * 8;
  const int br0 = cA0 >> 2, bg0 = ag0;
  const int br1 = (cA1 >> 2), bg1 = (cA1 & 3) ^ (((br1 >> 3) & 1) << 1);
  const ushort* pB0 = Bt + (size_t)(col0 + br0) * K + bg0 * 8;
  const ushort* pB1 = Bt + (size_t)(col0 + br1) * K + bg1 * 8;

  auto stA = [&](int u, int s) {
    ushort* dst = sA + (size_t)(((u & 1) * 2 + s) * BM) * 32;
    int kb = u * 64 + s * 32;
    gload16(pA0 + kb, dst + cA0 * 8);
    if constexpr (BM == 256) gload16(pA1 + kb, dst + cA1 * 8);
  };
  auto stB = [&](int u, int s) {
    ushort* dst = sB + (size_t)(((u & 1) * 2 + s) * 256) * 32;
    int kb = u * 64 + s * 32;
    gload16(pB0 + kb, dst + cA0 * 8);
    gload16(pB1 + kb, dst + cA1 * 8);
  };
  auto rdA = [&](int buf, int s, int mf) -> bf16x8 {
    int row = wrow * (BM / 2) + mf * 16 + fr;
    int g = fc ^ (((row >> 3) & 1) << 1);
    return *(const bf16x8*)(sA + (size_t)((buf * 2 + s) * BM + row) * 32 + g * 8);
  };
  auto rdB = [&](int buf, int s, int nf) -> bf16x8 {
    int row = wcol * 64 + nf * 16 + fr;
    int g = fc ^ (((row >> 3) & 1) << 1);
    return *(const bf16x8*)(sB + (size_t)((buf * 2 + s) * 256 + row) * 32 + g * 8);
  };

#define VM_W() do { if constexpr (BM == 256) asm volatile("s_waitcnt vmcnt(4)" ::: "memory"); \
                    else                     asm volatile("s_waitcnt vmcnt(3)" ::: "memory"); } while (0)
#define BAR_SOFT() __builtin_amdgcn_s_barrier()
#define BAR_DATA() do { __builtin_amdgcn_s_barrier(); __builtin_amdgcn_sched_barrier(0); } while (0)

  f32x4 acc[MFR][4] = {};

  // prologue: stage tile 0 in consumption order
  stA(0, 0); stB(0, 0); stA(0, 1); stB(0, 1);
  VM_W();
  BAR_DATA();

  for (int t = 0; t < NT; ++t) {
    const int buf = t & 1;
    const bool more = (t + 1 < NT);
    bf16x8 aF[MH], bF[4];

    // ---- phase 0: (ksub 0, m-half 0) ----
#pragma unroll
    for (int mf = 0; mf < MH; ++mf) aF[mf] = rdA(buf, 0, mf);
#pragma unroll
    for (int nf = 0; nf < 4; ++nf) bF[nf] = rdB(buf, 0, nf);
    if (more) stA(t + 1, 0);
    BAR_SOFT();
    __builtin_amdgcn_s_setprio(1);
#pragma unroll
    for (int mf = 0; mf < MH; ++mf)
#pragma unroll
      for (int nf = 0; nf < 4; ++nf)
        acc[mf][nf] = __builtin_amdgcn_mfma_f32_16x16x32_bf16(aF[mf], bF[nf], acc[mf][nf], 0, 0, 0);
    __builtin_amdgcn_s_setprio(0);
    BAR_SOFT();

    // ---- phase 1: (ksub 0, m-half 1) ----
#pragma unroll
    for (int mf = 0; mf < MH; ++mf) aF[mf] = rdA(buf, 0, MH + mf);
    if (more) stB(t + 1, 0);
    BAR_SOFT();
    __builtin_amdgcn_s_setprio(1);
#pragma unroll
    for (int mf = 0; mf < MH; ++mf)
#pragma unroll
      for (int nf = 0; nf < 4; ++nf)
        acc[MH + mf][nf] = __builtin_amdgcn_mfma_f32_16x16x32_bf16(aF[mf], bF[nf], acc[MH + mf][nf], 0, 0, 0);
    __builtin_amdgcn_s_setprio(0);
    if (t == NT - 1) asm volatile("s_waitcnt vmcnt(0)" ::: "memory");
    else VM_W();
    BAR_DATA();

    // ---- phase 2: (ksub 1, m-half 0) ----
#pragma unroll
    for (int mf = 0; mf < MH; ++mf) aF[mf] = rdA(buf, 1, mf);
#pragma unroll
    for (int nf = 0; nf < 4; ++nf) bF[nf] = rdB(buf, 1, nf);
    if (more) stA(t + 1, 1);
    BAR_SOFT();
    __builtin_amdgcn_s_setprio(1);
#pragma unroll
    for (int mf = 0; mf < MH; ++mf)
#pragma unroll
      for (int nf = 0; nf < 4; ++nf)
        acc[mf][nf] = __builtin_amdgcn_mfma_f32_16x16x32_bf16(aF[mf], bF[nf], acc[mf][nf], 0, 0, 0);
    __builtin_amdgcn_s_setprio(0);
    BAR_SOFT();

    // ---- phase 3: (ksub 1, m-half 1) ----
#pragma unroll
    for (int mf = 0; mf < MH; ++mf) aF[mf] = rdA(buf, 1, MH + mf);
    if (more) stB(t + 1, 1);
    BAR_SOFT();
    __builtin_amdgcn_s_setprio(1);
#pragma unroll
    for (int mf = 0; mf < MH; ++mf)
#pragma unroll
      for (int nf = 0; nf < 4; ++nf)
        acc[MH + mf][nf] = __builtin_amdgcn_mfma_f32_16x16x32_bf16(aF[mf], bF[nf], acc[MH + mf][nf], 0, 0, 0);
    __builtin_amdgcn_s_setprio(0);
    if (more) VM_W();
    BAR_DATA();
  }
#undef VM_W
#undef BAR_SOFT
#undef BAR_DATA

  // ---- epilogue ----
#pragma unroll
  for (int nf = 0; nf < 4; ++nf) {
    int col = col0 + wcol * 64 + nf * 16 + fr;
    if (col >= N) continue;
    float bv = bias ? bias[col] : 0.f;
#pragma unroll
    for (int mf = 0; mf < MFR; ++mf) {
#pragma unroll
      for (int rr = 0; rr < 4; ++rr) {
        int row = row0 + wrow * (BM / 2) + mf * 16 + fc * 4 + rr;
        if (row >= M) continue;
        float v = acc[mf][nf][rr] + bv;
        if (ep) v = 0.5f * v * (1.0f + erff(v * 0.70710678118654752f));
        if (resid) v += resid[(size_t)row * N + col];
        if (obf) ((ushort*)Cv)[(size_t)row * N + col] = f2b(v);
        else     ((float*)Cv)[(size_t)row * N + col]  = v;
      }
    }
  }
}

// ---------------- 128x128 bf16 MFMA GEMM (head only) ----------------
template<int EP, int RESID, int OBF>
__global__ __launch_bounds__(256) void gemm_bt(const ushort* __restrict__ A,
                                               const ushort* __restrict__ Bt,
                                               const float* __restrict__ bias,
                                               const float* __restrict__ resid,
                                               void* __restrict__ C,
                                               int M, int N, int K) {
  __shared__ ushort As[128 * 32];
  __shared__ ushort Bs[128 * 32];
  int tid = threadIdx.x;
  int w = tid >> 6, l = tid & 63;
  int fr = l & 15, fc = l >> 4;
  int row0 = blockIdx.y * 128, col0 = blockIdx.x * 128;
  int wr = (w >> 1) * 64, wc = (w & 1) * 64;

  int srow0 = w * 32 + (l >> 2);
  int srow1 = srow0 + 16;
  int sc0 = (((l & 3) ^ ((srow0 >> 1) & 3)) << 3);
  int sc1 = (((l & 3) ^ ((srow1 >> 1) & 3)) << 3);
  const ushort* ga0 = A  + (size_t)(row0 + srow0) * K + sc0;
  const ushort* ga1 = A  + (size_t)(row0 + srow1) * K + sc1;
  const ushort* gb0 = Bt + (size_t)(col0 + srow0) * K + sc0;
  const ushort* gb1 = Bt + (size_t)(col0 + srow1) * K + sc1;

  int idxA[4], idxB[4];
#pragma unroll
  for (int m = 0; m < 4; ++m) {
    int rA = wr + m * 16 + fr;
    idxA[m] = rA * 32 + ((fc ^ ((rA >> 1) & 3)) << 3);
  }
#pragma unroll
  for (int n = 0; n < 4; ++n) {
    int rB = wc + n * 16 + fr;
    idxB[n] = rB * 32 + ((fc ^ ((rB >> 1) & 3)) << 3);
  }

  f32x4 acc[4][4] = {};

  for (int k0 = 0; k0 < K; k0 += 32) {
    gload16(ga0 + k0, &As[w * 1024]);
    gload16(ga1 + k0, &As[w * 1024 + 512]);
    gload16(gb0 + k0, &Bs[w * 1024]);
    gload16(gb1 + k0, &Bs[w * 1024 + 512]);
    __syncthreads();
    bf16x8 af[4], bfr[4];
#pragma unroll
    for (int m = 0; m < 4; ++m) af[m] = *(const bf16x8*)(As + idxA[m]);
#pragma unroll
    for (int n = 0; n < 4; ++n) bfr[n] = *(const bf16x8*)(Bs + idxB[n]);
#pragma unroll
    for (int m = 0; m < 4; ++m)
#pragma unroll
      for (int n = 0; n < 4; ++n)
        acc[m][n] = __builtin_amdgcn_mfma_f32_16x16x32_bf16(af[m], bfr[n], acc[m][n], 0, 0, 0);
    __syncthreads();
  }

#pragma unroll
  for (int n = 0; n < 4; ++n) {
    int col = col0 + wc + n * 16 + fr;
    if (col >= N) continue;
    float bv = bias ? bias[col] : 0.f;
#pragma unroll
    for (int m = 0; m < 4; ++m) {
#pragma unroll
      for (int rr = 0; rr < 4; ++rr) {
        int row = row0 + wr + m * 16 + fc * 4 + rr;
        if (row >= M) continue;
        float v = acc[m][n][rr] + bv;
        if (EP == 1) v = 0.5f * v * (1.0f + erff(v * 0.70710678118654752f));
        if (RESID) v += resid[(size_t)row * N + col];
        if (OBF) ((ushort*)C)[(size_t)row * N + col] = f2b(v);
        else     ((float*)C)[(size_t)row * N + col]  = v;
      }
    }
  }
}

// ---------------- MFMA flash attention ----------------
__global__ __launch_bounds__(256) void attn_mfma(const ushort* __restrict__ qkv,
                                                 ushort* __restrict__ aout) {
  int bid = blockIdx.x;
  int qt = bid & 3;
  int h  = (bid >> 2) % NH;
  int b  = (bid >> 2) / NH;
  int tid = threadIdx.x, w = tid >> 6, l = tid & 63;
  int fr = l & 15, fc = l >> 4;

  __shared__ ushort Vt[64 * 64];        // swizzled V^T tile [d][key]
  __shared__ ushort Pl[4 * 16 * 64];    // per-wave P [qrow][key], swizzled

  const size_t brow = (size_t)b * NTOK;
  int q0 = qt * 64 + w * 16;

  bf16x8 qf[2];
  {
    const ushort* qp = qkv + (brow + q0 + fr) * 2304 + h * 64 + fc * 8;
    qf[0] = *(const bf16x8*)qp;
    qf[1] = *(const bf16x8*)(qp + 32);
  }
  float rs[4] = {0.f, 0.f, 0.f, 0.f};
  f32x4 oc[4] = {};

  for (int kt = 0; kt < 4; ++kt) {
    __syncthreads();
    {
      int key = tid >> 2, d0 = (tid & 3) * 16;
      int j = kt * 64 + key;
      bool valid = j < NTOK;
      const ushort* vp = qkv + (brow + j) * 2304 + 1536 + h * 64 + d0;
      ushort vbuf[16];
      if (valid) {
        *(bf16x8*)(vbuf)     = *(const bf16x8*)vp;
        *(bf16x8*)(vbuf + 8) = *(const bf16x8*)(vp + 8);
      } else {
#pragma unroll
        for (int i = 0; i < 16; ++i) vbuf[i] = 0;
      }
#pragma unroll
      for (int i = 0; i < 16; ++i) {
        int d = d0 + i;
        int byte = d * 128 + ((((key >> 3)) ^ (d & 7)) << 4) + (key & 7) * 2;
        Vt[byte >> 1] = vbuf[i];
      }
    }
    f32x4 sc[4];
#pragma unroll
    for (int n = 0; n < 4; ++n) {
      f32x4 z = {};
      const ushort* kp = qkv + (brow + kt * 64 + n * 16 + fr) * 2304 + 768 + h * 64 + fc * 8;
      bf16x8 k0 = *(const bf16x8*)kp;
      bf16x8 k1 = *(const bf16x8*)(kp + 32);
      z = __builtin_amdgcn_mfma_f32_16x16x32_bf16(qf[0], k0, z, 0, 0, 0);
      z = __builtin_amdgcn_mfma_f32_16x16x32_bf16(qf[1], k1, z, 0, 0, 0);
      sc[n] = z;
    }
    float part[4] = {0.f, 0.f, 0.f, 0.f};
#pragma unroll
    for (int n = 0; n < 4; ++n) {
      int j = kt * 64 + n * 16 + fr;
      bool jv = j < NTOK;
#pragma unroll
      for (int rr = 0; rr < 4; ++rr) {
        float e = jv ? __expf(sc[n][rr] * 0.125f) : 0.f;
        part[rr] += e;
        int row = fc * 4 + rr, col = n * 16 + fr;
        int byte = row * 128 + (((col >> 3) ^ (row & 7)) << 4) + (col & 7) * 2;
        Pl[w * 1024 + (byte >> 1)] = f2b(e);
      }
    }
#pragma unroll
    for (int rr = 0; rr < 4; ++rr) {
      float p = part[rr];
      p += __shfl_xor(p, 1); p += __shfl_xor(p, 2);
      p += __shfl_xor(p, 4); p += __shfl_xor(p, 8);
      rs[rr] += p;
    }
    __syncthreads();
#pragma unroll
    for (int ks = 0; ks < 2; ++ks) {
      int prow = fr;
      int pbyte = prow * 128 + (((ks * 4 + fc) ^ (prow & 7)) << 4);
      bf16x8 pf = *(const bf16x8*)(Pl + w * 1024 + (pbyte >> 1));
#pragma unroll
      for (int n = 0; n < 4; ++n) {
        int d = n * 16 + fr;
        int vb = d * 128 + (((ks * 4 + fc) ^ (d & 7)) << 4);
        bf16x8 vf = *(const bf16x8*)(Vt + (vb >> 1));
        oc[n] = __builtin_amdgcn_mfma_f32_16x16x32_bf16(pf, vf, oc[n], 0, 0, 0);
      }
    }
  }
#pragma unroll
  for (int n = 0; n < 4; ++n) {
#pragma unroll
    for (int rr = 0; rr < 4; ++rr) {
      int qq = q0 + fc * 4 + rr;
      if (qq < NTOK) {
        float v = oc[n][rr] / (rs[rr] + 1e-8f);
        aout[(brow + qq) * 768 + h * 64 + n * 16 + fr] = f2b(v);
      }
    }
  }
}

// ---------------- host launch ----------------
extern "C" void kernel_launch(void* const* d_in, const int* in_sizes, int n_in,
                              void* d_out, int out_size, void* d_ws, size_t ws_size,
                              hipStream_t stream) {
  const float* img       = (const float*)d_in[0];
  const float* p_ln1_g   = (const float*)d_in[1];
  const float* p_ln1_b   = (const float*)d_in[2];
  const float* patch_w   = (const float*)d_in[3];
  const float* patch_b   = (const float*)d_in[4];
  const float* p_ln2_g   = (const float*)d_in[5];
  const float* p_ln2_b   = (const float*)d_in[6];
  const float* pos_emb   = (const float*)d_in[7];
  const float* cls_tok   = (const float*)d_in[8];
  const float* attn_ln_g = (const float*)d_in[9];
  const float* attn_ln_b = (const float*)d_in[10];
  const float* w_qkv     = (const float*)d_in[11];
  const float* w_out     = (const float*)d_in[12];
  const float* b_out     = (const float*)d_in[13];
  const float* ff_ln_g   = (const float*)d_in[14];
  const float* ff_ln_b   = (const float*)d_in[15];
  const float* ff_w1     = (const float*)d_in[16];
  const float* ff_b1     = (const float*)d_in[17];
  const float* ff_w2     = (const float*)d_in[18];
  const float* ff_b2     = (const float*)d_in[19];
  const float* fin_ln_g  = (const float*)d_in[20];
  const float* fin_ln_b  = (const float*)d_in[21];
  const float* head_w    = (const float*)d_in[22];
  const float* head_b    = (const float*)d_in[23];
  float* out = (float*)d_out;

  (void)hipFuncSetAttribute((const void*)gemm8p<256>,
                            hipFuncAttributeMaxDynamicSharedMemorySize, 131072);
  (void)hipFuncSetAttribute((const void*)gemm8p<128>,
                            hipFuncAttributeMaxDynamicSharedMemorySize, 98304);

  // ---- workspace carve ----
  char* p = (char*)d_ws;
  auto alloc = [&](size_t bytes) { char* r = p; p += (bytes + 255) & ~(size_t)255; return r; };
  float*  x      = (float*) alloc((size_t)ROWS_PAD * 768 * 4);
  ushort* xnb    = (ushort*)alloc((size_t)ROWS_PAD * 768 * 2);
  ushort* qkvb   = (ushort*)alloc((size_t)ROWS_PAD * 2304 * 2);
  ushort* aoutb  = (ushort*)alloc((size_t)ROWS_PAD * 768 * 2);
  ushort* wtq    = (ushort*)alloc((size_t)2304 * 768 * 2);
  ushort* wto    = (ushort*)alloc((size_t)768 * 768 * 2);
  ushort* wt1    = (ushort*)alloc((size_t)3072 * 768 * 2);
  ushort* wt2    = (ushort*)alloc((size_t)768 * 3072 * 2);
  ushort* pwt    = (ushort*)alloc((size_t)768 * 768 * 2);
  ushort* hwt    = (ushort*)alloc((size_t)1024 * 768 * 2);
  ushort* xclsb  = (ushort*)alloc((size_t)128 * 768 * 2);
  ushort* hidb   = qkvb;                 // [ROWS_PAD][3072] aliases qkvb+aoutb
  ushort* xpb    = xnb;                  // patch LN1 out (12544 rows)
  float*  xe     = (float*)qkvb;         // patch GEMM out fp32 (pre-loop only)

  dim3 blk(256), blk8(512), tblk(32, 8);

  // ---- patch embedding ----
  transpose_cast<<<dim3(24, 24), tblk, 0, stream>>>(patch_w, pwt, 768, 768);
  transpose_cast<<<dim3(32, 24), tblk, 0, stream>>>(head_w, hwt, 768, 1000);
  patch_ln1<<<PROWS, blk, 0, stream>>>(img, p_ln1_g, p_ln1_b, xpb);
  gemm8p<256><<<dim3(3, 49), blk8, 131072, stream>>>(xpb, pwt, patch_b, nullptr, xe,
                                                     PROWS, 768, 768, 0, 0);
  ln2_pos<<<PROWS, blk, 0, stream>>>(xe, p_ln2_g, p_ln2_b, pos_emb, x);
  cls_init<<<B_, blk, 0, stream>>>(cls_tok, pos_emb, x);

  for (int l = 0; l < NL; ++l) {
    transpose4<<<6912, tblk, 0, stream>>>(w_qkv + (size_t)l * 768 * 2304,
                                          w_out + (size_t)l * 768 * 768,
                                          ff_w1 + (size_t)l * 768 * MFF,
                                          ff_w2 + (size_t)l * MFF * 768,
                                          wtq, wto, wt1, wt2);

    ln_rows_b<<<ROWS, blk, 0, stream>>>(x, 768, attn_ln_g + (size_t)l * 768,
                                        attn_ln_b + (size_t)l * 768, xnb);
    gemm8p<256><<<dim3(9, 50), blk8, 131072, stream>>>(xnb, wtq, nullptr, nullptr, qkvb,
                                                       ROWS, 2304, 768, 0, 1);
    attn_mfma<<<B_ * NH * 4, blk, 0, stream>>>(qkvb, aoutb);
    gemm8p<128><<<dim3(3, 99), blk8, 98304, stream>>>(aoutb, wto, b_out + (size_t)l * 768,
                                                      x, x, ROWS, 768, 768, 0, 0);
    ln_rows_b<<<ROWS, blk, 0, stream>>>(x, 768, ff_ln_g + (size_t)l * 768,
                                        ff_ln_b + (size_t)l * 768, xnb);
    gemm8p<256><<<dim3(12, 50), blk8, 131072, stream>>>(xnb, wt1, ff_b1 + (size_t)l * MFF,
                                                        nullptr, hidb, ROWS, MFF, 768, 1, 1);
    gemm8p<128><<<dim3(3, 99), blk8, 98304, stream>>>(hidb, wt2, ff_b2 + (size_t)l * 768,
                                                      x, x, ROWS, 768, MFF, 0, 0);
  }

  // ---- final LN (cls rows) + head ----
  ln_rows_b<<<B_, blk, 0, stream>>>(x, (long)NTOK * 768, fin_ln_g, fin_ln_b, xclsb);
  gemm_bt<0, 0, 0><<<dim3(8, 1), blk, 0, stream>>>(xclsb, hwt, head_b, nullptr, out,
                                                   B_, NCLS, 768);
}

// Round 5
// 5678.745 us; speedup vs baseline: 1.2112x; 1.1885x over previous
//
#include <hip/hip_runtime.h>
#include <hip/hip_bf16.h>
#include <math.h>

// ---- problem constants ----
#define B_     64
#define NTOK   197
#define NPATCH 196
#define D768   768
#define NL     12
#define NH     12
#define MFF    3072
#define NCLS   1000
#define ROWS   (B_ * NTOK)      // 12608
#define PROWS  (B_ * NPATCH)    // 12544
#define ROWS_PAD 12672          // 99 * 128

typedef unsigned short ushort;
typedef __bf16 bf16x8 __attribute__((ext_vector_type(8)));
typedef float  f32x4  __attribute__((ext_vector_type(4)));
typedef unsigned short u16x4 __attribute__((ext_vector_type(4)));

__device__ __forceinline__ ushort f2b(float f) {
  __hip_bfloat16 h = __float2bfloat16(f);
  return *reinterpret_cast<ushort*>(&h);
}

__device__ __forceinline__ void gload16(const ushort* g, ushort* lds) {
  __builtin_amdgcn_global_load_lds((const __attribute__((address_space(1))) void*)g,
                                   (__attribute__((address_space(3))) void*)lds, 16, 0, 0);
}

// ---------------- block-wide mean/rstd over 768 elems (256 threads) ----------------
__device__ __forceinline__ void block_mean_rstd(float s, float sq, float& mean, float& rstd) {
#pragma unroll
  for (int off = 32; off; off >>= 1) { s += __shfl_xor(s, off); sq += __shfl_xor(sq, off); }
  __shared__ float ss[4], ssq[4];
  int w = threadIdx.x >> 6;
  if ((threadIdx.x & 63) == 0) { ss[w] = s; ssq[w] = sq; }
  __syncthreads();
  s  = ss[0] + ss[1] + ss[2] + ss[3];
  sq = ssq[0] + ssq[1] + ssq[2] + ssq[3];
  mean = s * (1.0f / 768.0f);
  float var = sq * (1.0f / 768.0f) - mean * mean;
  rstd = rsqrtf(var + 1e-5f);
}

// ---------------- LN over rows of 768 (fp32 in, bf16 out) ----------------
__global__ __launch_bounds__(256) void ln_rows_b(const float* __restrict__ in, long in_stride,
                                                 const float* __restrict__ g,
                                                 const float* __restrict__ bta,
                                                 ushort* __restrict__ out) {
  const float* xr = in + (size_t)blockIdx.x * in_stride;
  int t = threadIdx.x;
  float v0 = xr[t], v1 = xr[t + 256], v2 = xr[t + 512];
  float mean, rstd;
  block_mean_rstd(v0 + v1 + v2, v0 * v0 + v1 * v1 + v2 * v2, mean, rstd);
  ushort* o = out + (size_t)blockIdx.x * 768;
  o[t]       = f2b((v0 - mean) * rstd * g[t]       + bta[t]);
  o[t + 256] = f2b((v1 - mean) * rstd * g[t + 256] + bta[t + 256]);
  o[t + 512] = f2b((v2 - mean) * rstd * g[t + 512] + bta[t + 512]);
}

// ---------------- patch extraction + LN1 (bf16 out) ----------------
__global__ __launch_bounds__(256) void patch_ln1(const float* __restrict__ img,
                                                 const float* __restrict__ g,
                                                 const float* __restrict__ bta,
                                                 ushort* __restrict__ xp) {
  int pidx = blockIdx.x;                 // b*196 + ph*14 + pw
  int b = pidx / NPATCH, hw = pidx % NPATCH;
  int ph = hw / 14, pw = hw % 14;
  int t = threadIdx.x;
  float v[3];
#pragma unroll
  for (int u = 0; u < 3; ++u) {
    int k = t + u * 256;                  // feature index (p1*16+p2)*3 + c
    int c = k % 3, p2 = (k / 3) & 15, p1 = k / 48;
    v[u] = img[(((size_t)b * 3 + c) * 224 + ph * 16 + p1) * 224 + pw * 16 + p2];
  }
  float mean, rstd;
  block_mean_rstd(v[0] + v[1] + v[2], v[0] * v[0] + v[1] * v[1] + v[2] * v[2], mean, rstd);
  ushort* o = xp + (size_t)pidx * 768;
#pragma unroll
  for (int u = 0; u < 3; ++u) { int k = t + u * 256; o[k] = f2b((v[u] - mean) * rstd * g[k] + bta[k]); }
}

// ---------------- LN2 + pos_emb, scatter into x at token 1+i (fp32) ----------------
__global__ __launch_bounds__(256) void ln2_pos(const float* __restrict__ xe,
                                               const float* __restrict__ g,
                                               const float* __restrict__ bta,
                                               const float* __restrict__ pos,
                                               float* __restrict__ x) {
  int pidx = blockIdx.x;
  int b = pidx / NPATCH, i = pidx % NPATCH;
  const float* xr = xe + (size_t)pidx * 768;
  int t = threadIdx.x;
  float v0 = xr[t], v1 = xr[t + 256], v2 = xr[t + 512];
  float mean, rstd;
  block_mean_rstd(v0 + v1 + v2, v0 * v0 + v1 * v1 + v2 * v2, mean, rstd);
  const float* p = pos + (size_t)(1 + i) * 768;
  float* o = x + ((size_t)b * NTOK + 1 + i) * 768;
  o[t]       = (v0 - mean) * rstd * g[t]       + bta[t]       + p[t];
  o[t + 256] = (v1 - mean) * rstd * g[t + 256] + bta[t + 256] + p[t + 256];
  o[t + 512] = (v2 - mean) * rstd * g[t + 512] + bta[t + 512] + p[t + 512];
}

// ---------------- cls token + pos_emb[0] ----------------
__global__ __launch_bounds__(256) void cls_init(const float* __restrict__ cls_tok,
                                                const float* __restrict__ pos,
                                                float* __restrict__ x) {
  int b = blockIdx.x, t = threadIdx.x;
  float* o = x + (size_t)b * NTOK * 768;
#pragma unroll
  for (int u = 0; u < 3; ++u) { int k = t + u * 256; o[k] = cls_tok[k] + pos[k]; }
}

// ---------------- cast + transpose: W fp32 [K][N] -> Wt bf16 [N][K] (bounds-checked) ----------------
__global__ __launch_bounds__(256) void transpose_cast(const float* __restrict__ W,
                                                      ushort* __restrict__ Wt,
                                                      int K, int N) {
  __shared__ float t[32][33];
  int n0 = blockIdx.x * 32, k0 = blockIdx.y * 32;
  int tx = threadIdx.x, ty = threadIdx.y;   // 32 x 8
#pragma unroll
  for (int u = 0; u < 32; u += 8) {
    int n = n0 + tx;
    t[ty + u][tx] = (n < N) ? W[(size_t)(k0 + ty + u) * N + n] : 0.f;
  }
  __syncthreads();
#pragma unroll
  for (int u = 0; u < 32; u += 8) {
    int n = n0 + ty + u;
    if (n < N) Wt[(size_t)n * K + k0 + tx] = f2b(t[tx][ty + u]);
  }
}

// ---------------- merged per-layer transposes (all dims %32==0, no bounds) ----------------
__global__ __launch_bounds__(256) void transpose4(const float* __restrict__ wq,
                                                  const float* __restrict__ wo,
                                                  const float* __restrict__ w1,
                                                  const float* __restrict__ w2,
                                                  ushort* __restrict__ tq,
                                                  ushort* __restrict__ to,
                                                  ushort* __restrict__ t1,
                                                  ushort* __restrict__ t2) {
  int bid = blockIdx.x;
  const float* W; ushort* Wt; int K, N, xt;
  if (bid < 1728)      {             W = wq; Wt = tq; K = 768;  N = 2304; xt = 72; }
  else if (bid < 2304) { bid -= 1728; W = wo; Wt = to; K = 768;  N = 768;  xt = 24; }
  else if (bid < 4608) { bid -= 2304; W = w1; Wt = t1; K = 768;  N = 3072; xt = 96; }
  else                 { bid -= 4608; W = w2; Wt = t2; K = 3072; N = 768;  xt = 24; }
  int n0 = (bid % xt) * 32, k0 = (bid / xt) * 32;
  __shared__ float t[32][33];
  int tx = threadIdx.x, ty = threadIdx.y;   // 32 x 8
#pragma unroll
  for (int u = 0; u < 32; u += 8)
    t[ty + u][tx] = W[(size_t)(k0 + ty + u) * N + n0 + tx];
  __syncthreads();
#pragma unroll
  for (int u = 0; u < 32; u += 8)
    Wt[(size_t)(n0 + ty + u) * K + k0 + tx] = f2b(t[tx][ty + u]);
}

// ================= bf16 MFMA GEMM v2: C = A @ Bt^T =================
// A [M][K] bf16, Bt [N][K] bf16 row-major. K % 64 == 0, N % 128 == 0, tile 128x128.
// BK=64, 256 thr / 4 waves (2x2), wave = 64x64 out as 4x4 frags of 16x16x32.
// SWAPPED operands: acc[m][n] = mfma(b,a) so lane holds 4 CONTIGUOUS cols
// (col = wc+n*16+fc*4+rr, row = wr+m*16+fr) -> vectorized epilogues:
//   fp32 path: dwordx4 resid-load + store (64B segments, no write-amp)
//   bf16 path: per-wave LDS restage -> ushort4 stores (128B-contiguous rows)
// LDS staging swizzle (both-sides involution): row's 8 16B-chunks stored with
// chunk slot d holding global chunk d ^ (row&7); reads use same XOR.
template<int EP, int RESID, int OBF>
__global__ __launch_bounds__(256) void gemm_v2(const ushort* __restrict__ A,
                                               const ushort* __restrict__ Bt,
                                               const float* __restrict__ bias,
                                               const float* __restrict__ resid,
                                               void* __restrict__ Cv,
                                               int M, int N, int K) {
  __shared__ ushort smem[2 * 128 * 64];     // As | Bs ; bf16 path reuses as C-stage
  ushort* As = smem;
  ushort* Bs = smem + 128 * 64;

  const int tid = threadIdx.x;
  const int w = tid >> 6, l = tid & 63;
  const int fr = l & 15, fc = l >> 4;
  const int row0 = blockIdx.y * 128, col0 = blockIdx.x * 128;
  const int wr = (w >> 1) * 64, wc = (w & 1) * 64;

  // staging: i=0..3; row = i*32 + w*8 + (l>>3); global chunk g = (l&7) ^ (l>>3)
  const int srow = w * 8 + (l >> 3);
  const int sg = (l & 7) ^ (l >> 3);
  const ushort* pA[4]; const ushort* pB[4];
#pragma unroll
  for (int i = 0; i < 4; ++i) {
    pA[i] = A  + (size_t)(row0 + i * 32 + srow) * K + sg * 8;
    pB[i] = Bt + (size_t)(col0 + i * 32 + srow) * K + sg * 8;
  }

  f32x4 acc[4][4] = {};

  for (int k0 = 0; k0 < K; k0 += 64) {
#pragma unroll
    for (int i = 0; i < 4; ++i) {
      gload16(pA[i] + k0, As + (i * 256 + w * 64) * 8);
      gload16(pB[i] + k0, Bs + (i * 256 + w * 64) * 8);
    }
    __syncthreads();
#pragma unroll
    for (int ks = 0; ks < 2; ++ks) {
      const int sw = ((ks * 4 + fc) ^ (fr & 7)) << 3;
      bf16x8 a_[4], b_[4];
#pragma unroll
      for (int m = 0; m < 4; ++m)
        a_[m] = *(const bf16x8*)(As + (wr + m * 16 + fr) * 64 + sw);
#pragma unroll
      for (int n = 0; n < 4; ++n)
        b_[n] = *(const bf16x8*)(Bs + (wc + n * 16 + fr) * 64 + sw);
#pragma unroll
      for (int m = 0; m < 4; ++m)
#pragma unroll
        for (int n = 0; n < 4; ++n)
          acc[m][n] = __builtin_amdgcn_mfma_f32_16x16x32_bf16(b_[n], a_[m], acc[m][n], 0, 0, 0);
    }
    __syncthreads();
  }

  if (!OBF) {
    // fp32 output, optional bias/gelu/resid; 16B loads/stores, 64B/row segments
    float* Cf = (float*)Cv;
#pragma unroll
    for (int m = 0; m < 4; ++m) {
      int row = row0 + wr + m * 16 + fr;
      if (row >= M) continue;
#pragma unroll
      for (int n = 0; n < 4; ++n) {
        int col = col0 + wc + n * 16 + fc * 4;
        f32x4 v = acc[m][n];
        if (bias) v += *(const f32x4*)(bias + col);
        if (EP) {
#pragma unroll
          for (int rr = 0; rr < 4; ++rr)
            v[rr] = 0.5f * v[rr] * (1.0f + erff(v[rr] * 0.70710678118654752f));
        }
        if (RESID) v += *(const f32x4*)(resid + (size_t)row * N + col);
        *(f32x4*)(Cf + (size_t)row * N + col) = v;
      }
    }
  } else {
    // bf16 output: restage wave's 64x64 tile via LDS (8B-slot swizzle), then
    // ushort4 stores covering full 128B rows.
    ushort* Cw = smem + w * 4096;           // 64*64 elems per wave
#pragma unroll
    for (int m = 0; m < 4; ++m) {
      int rl = m * 16 + fr;
#pragma unroll
      for (int n = 0; n < 4; ++n) {
        int col = col0 + wc + n * 16 + fc * 4;
        f32x4 v = acc[m][n];
        if (bias) v += *(const f32x4*)(bias + col);
        if (EP) {
#pragma unroll
          for (int rr = 0; rr < 4; ++rr)
            v[rr] = 0.5f * v[rr] * (1.0f + erff(v[rr] * 0.70710678118654752f));
        }
        u16x4 pk = { f2b(v[0]), f2b(v[1]), f2b(v[2]), f2b(v[3]) };
        int s = (n * 4 + fc) ^ (rl & 7);
        *(u16x4*)(Cw + rl * 64 + s * 4) = pk;
      }
    }
    // wave-local readout (compiler inserts lgkmcnt for the LDS RAW dep)
    ushort* Cb = (ushort*)Cv;
#pragma unroll
    for (int pp = 0; pp < 16; ++pp) {
      int rl = pp * 4 + (l >> 4);
      int cs = l & 15;
      u16x4 pk = *(const u16x4*)(Cw + rl * 64 + ((cs ^ (rl & 7)) * 4));
      int row = row0 + wr + rl;
      if (row < M) *(u16x4*)(Cb + (size_t)row * N + col0 + wc + cs * 4) = pk;
    }
  }
}

// ---------------- 128x128 bf16 MFMA GEMM (head only, N-bounds-safe) ----------------
template<int EP, int RESID, int OBF>
__global__ __launch_bounds__(256) void gemm_bt(const ushort* __restrict__ A,
                                               const ushort* __restrict__ Bt,
                                               const float* __restrict__ bias,
                                               const float* __restrict__ resid,
                                               void* __restrict__ C,
                                               int M, int N, int K) {
  __shared__ ushort As[128 * 32];
  __shared__ ushort Bs[128 * 32];
  int tid = threadIdx.x;
  int w = tid >> 6, l = tid & 63;
  int fr = l & 15, fc = l >> 4;
  int row0 = blockIdx.y * 128, col0 = blockIdx.x * 128;
  int wr = (w >> 1) * 64, wc = (w & 1) * 64;

  int srow0 = w * 32 + (l >> 2);
  int srow1 = srow0 + 16;
  int sc0 = (((l & 3) ^ ((srow0 >> 1) & 3)) << 3);
  int sc1 = (((l & 3) ^ ((srow1 >> 1) & 3)) << 3);
  const ushort* ga0 = A  + (size_t)(row0 + srow0) * K + sc0;
  const ushort* ga1 = A  + (size_t)(row0 + srow1) * K + sc1;
  const ushort* gb0 = Bt + (size_t)(col0 + srow0) * K + sc0;
  const ushort* gb1 = Bt + (size_t)(col0 + srow1) * K + sc1;

  int idxA[4], idxB[4];
#pragma unroll
  for (int m = 0; m < 4; ++m) {
    int rA = wr + m * 16 + fr;
    idxA[m] = rA * 32 + ((fc ^ ((rA >> 1) & 3)) << 3);
  }
#pragma unroll
  for (int n = 0; n < 4; ++n) {
    int rB = wc + n * 16 + fr;
    idxB[n] = rB * 32 + ((fc ^ ((rB >> 1) & 3)) << 3);
  }

  f32x4 acc[4][4] = {};

  for (int k0 = 0; k0 < K; k0 += 32) {
    gload16(ga0 + k0, &As[w * 1024]);
    gload16(ga1 + k0, &As[w * 1024 + 512]);
    gload16(gb0 + k0, &Bs[w * 1024]);
    gload16(gb1 + k0, &Bs[w * 1024 + 512]);
    __syncthreads();
    bf16x8 af[4], bfr[4];
#pragma unroll
    for (int m = 0; m < 4; ++m) af[m] = *(const bf16x8*)(As + idxA[m]);
#pragma unroll
    for (int n = 0; n < 4; ++n) bfr[n] = *(const bf16x8*)(Bs + idxB[n]);
#pragma unroll
    for (int m = 0; m < 4; ++m)
#pragma unroll
      for (int n = 0; n < 4; ++n)
        acc[m][n] = __builtin_amdgcn_mfma_f32_16x16x32_bf16(af[m], bfr[n], acc[m][n], 0, 0, 0);
    __syncthreads();
  }

#pragma unroll
  for (int n = 0; n < 4; ++n) {
    int col = col0 + wc + n * 16 + fr;
    if (col >= N) continue;
    float bv = bias ? bias[col] : 0.f;
#pragma unroll
    for (int m = 0; m < 4; ++m) {
#pragma unroll
      for (int rr = 0; rr < 4; ++rr) {
        int row = row0 + wr + m * 16 + fc * 4 + rr;
        if (row >= M) continue;
        float v = acc[m][n][rr] + bv;
        if (EP == 1) v = 0.5f * v * (1.0f + erff(v * 0.70710678118654752f));
        if (RESID) v += resid[(size_t)row * N + col];
        if (OBF) ((ushort*)C)[(size_t)row * N + col] = f2b(v);
        else     ((float*)C)[(size_t)row * N + col]  = v;
      }
    }
  }
}

// ---------------- MFMA flash attention ----------------
__global__ __launch_bounds__(256) void attn_mfma(const ushort* __restrict__ qkv,
                                                 ushort* __restrict__ aout) {
  int bid = blockIdx.x;
  int qt = bid & 3;
  int h  = (bid >> 2) % NH;
  int b  = (bid >> 2) / NH;
  int tid = threadIdx.x, w = tid >> 6, l = tid & 63;
  int fr = l & 15, fc = l >> 4;

  __shared__ ushort Vt[64 * 64];        // swizzled V^T tile [d][key]
  __shared__ ushort Pl[4 * 16 * 64];    // per-wave P [qrow][key], swizzled

  const size_t brow = (size_t)b * NTOK;
  int q0 = qt * 64 + w * 16;

  bf16x8 qf[2];
  {
    const ushort* qp = qkv + (brow + q0 + fr) * 2304 + h * 64 + fc * 8;
    qf[0] = *(const bf16x8*)qp;
    qf[1] = *(const bf16x8*)(qp + 32);
  }
  float rs[4] = {0.f, 0.f, 0.f, 0.f};
  f32x4 oc[4] = {};

  for (int kt = 0; kt < 4; ++kt) {
    __syncthreads();
    {
      int key = tid >> 2, d0 = (tid & 3) * 16;
      int j = kt * 64 + key;
      bool valid = j < NTOK;
      const ushort* vp = qkv + (brow + j) * 2304 + 1536 + h * 64 + d0;
      ushort vbuf[16];
      if (valid) {
        *(bf16x8*)(vbuf)     = *(const bf16x8*)vp;
        *(bf16x8*)(vbuf + 8) = *(const bf16x8*)(vp + 8);
      } else {
#pragma unroll
        for (int i = 0; i < 16; ++i) vbuf[i] = 0;
      }
#pragma unroll
      for (int i = 0; i < 16; ++i) {
        int d = d0 + i;
        int byte = d * 128 + ((((key >> 3)) ^ (d & 7)) << 4) + (key & 7) * 2;
        Vt[byte >> 1] = vbuf[i];
      }
    }
    f32x4 sc[4];
#pragma unroll
    for (int n = 0; n < 4; ++n) {
      f32x4 z = {};
      const ushort* kp = qkv + (brow + kt * 64 + n * 16 + fr) * 2304 + 768 + h * 64 + fc * 8;
      bf16x8 k0 = *(const bf16x8*)kp;
      bf16x8 k1 = *(const bf16x8*)(kp + 32);
      z = __builtin_amdgcn_mfma_f32_16x16x32_bf16(qf[0], k0, z, 0, 0, 0);
      z = __builtin_amdgcn_mfma_f32_16x16x32_bf16(qf[1], k1, z, 0, 0, 0);
      sc[n] = z;
    }
    float part[4] = {0.f, 0.f, 0.f, 0.f};
#pragma unroll
    for (int n = 0; n < 4; ++n) {
      int j = kt * 64 + n * 16 + fr;
      bool jv = j < NTOK;
#pragma unroll
      for (int rr = 0; rr < 4; ++rr) {
        float e = jv ? __expf(sc[n][rr] * 0.125f) : 0.f;
        part[rr] += e;
        int row = fc * 4 + rr, col = n * 16 + fr;
        int byte = row * 128 + (((col >> 3) ^ (row & 7)) << 4) + (col & 7) * 2;
        Pl[w * 1024 + (byte >> 1)] = f2b(e);
      }
    }
#pragma unroll
    for (int rr = 0; rr < 4; ++rr) {
      float p = part[rr];
      p += __shfl_xor(p, 1); p += __shfl_xor(p, 2);
      p += __shfl_xor(p, 4); p += __shfl_xor(p, 8);
      rs[rr] += p;
    }
    __syncthreads();
#pragma unroll
    for (int ks = 0; ks < 2; ++ks) {
      int prow = fr;
      int pbyte = prow * 128 + (((ks * 4 + fc) ^ (prow & 7)) << 4);
      bf16x8 pf = *(const bf16x8*)(Pl + w * 1024 + (pbyte >> 1));
#pragma unroll
      for (int n = 0; n < 4; ++n) {
        int d = n * 16 + fr;
        int vb = d * 128 + (((ks * 4 + fc) ^ (d & 7)) << 4);
        bf16x8 vf = *(const bf16x8*)(Vt + (vb >> 1));
        oc[n] = __builtin_amdgcn_mfma_f32_16x16x32_bf16(pf, vf, oc[n], 0, 0, 0);
      }
    }
  }
#pragma unroll
  for (int n = 0; n < 4; ++n) {
#pragma unroll
    for (int rr = 0; rr < 4; ++rr) {
      int qq = q0 + fc * 4 + rr;
      if (qq < NTOK) {
        float v = oc[n][rr] / (rs[rr] + 1e-8f);
        aout[(brow + qq) * 768 + h * 64 + n * 16 + fr] = f2b(v);
      }
    }
  }
}

// ---------------- host launch ----------------
extern "C" void kernel_launch(void* const* d_in, const int* in_sizes, int n_in,
                              void* d_out, int out_size, void* d_ws, size_t ws_size,
                              hipStream_t stream) {
  const float* img       = (const float*)d_in[0];
  const float* p_ln1_g   = (const float*)d_in[1];
  const float* p_ln1_b   = (const float*)d_in[2];
  const float* patch_w   = (const float*)d_in[3];
  const float* patch_b   = (const float*)d_in[4];
  const float* p_ln2_g   = (const float*)d_in[5];
  const float* p_ln2_b   = (const float*)d_in[6];
  const float* pos_emb   = (const float*)d_in[7];
  const float* cls_tok   = (const float*)d_in[8];
  const float* attn_ln_g = (const float*)d_in[9];
  const float* attn_ln_b = (const float*)d_in[10];
  const float* w_qkv     = (const float*)d_in[11];
  const float* w_out     = (const float*)d_in[12];
  const float* b_out     = (const float*)d_in[13];
  const float* ff_ln_g   = (const float*)d_in[14];
  const float* ff_ln_b   = (const float*)d_in[15];
  const float* ff_w1     = (const float*)d_in[16];
  const float* ff_b1     = (const float*)d_in[17];
  const float* ff_w2     = (const float*)d_in[18];
  const float* ff_b2     = (const float*)d_in[19];
  const float* fin_ln_g  = (const float*)d_in[20];
  const float* fin_ln_b  = (const float*)d_in[21];
  const float* head_w    = (const float*)d_in[22];
  const float* head_b    = (const float*)d_in[23];
  float* out = (float*)d_out;

  // ---- workspace carve ----
  char* p = (char*)d_ws;
  auto alloc = [&](size_t bytes) { char* r = p; p += (bytes + 255) & ~(size_t)255; return r; };
  float*  x      = (float*) alloc((size_t)ROWS_PAD * 768 * 4);
  ushort* xnb    = (ushort*)alloc((size_t)ROWS_PAD * 768 * 2);
  ushort* qkvb   = (ushort*)alloc((size_t)ROWS_PAD * 2304 * 2);
  ushort* aoutb  = (ushort*)alloc((size_t)ROWS_PAD * 768 * 2);
  ushort* wtq    = (ushort*)alloc((size_t)2304 * 768 * 2);
  ushort* wto    = (ushort*)alloc((size_t)768 * 768 * 2);
  ushort* wt1    = (ushort*)alloc((size_t)3072 * 768 * 2);
  ushort* wt2    = (ushort*)alloc((size_t)768 * 3072 * 2);
  ushort* pwt    = (ushort*)alloc((size_t)768 * 768 * 2);
  ushort* hwt    = (ushort*)alloc((size_t)1024 * 768 * 2);
  ushort* xclsb  = (ushort*)alloc((size_t)128 * 768 * 2);
  ushort* hidb   = qkvb;                 // [ROWS_PAD][3072] aliases qkvb+aoutb
  ushort* xpb    = xnb;                  // patch LN1 out (12544 rows)
  float*  xe     = (float*)qkvb;         // patch GEMM out fp32 (pre-loop only)

  dim3 blk(256), tblk(32, 8);

  // ---- patch embedding ----
  transpose_cast<<<dim3(24, 24), tblk, 0, stream>>>(patch_w, pwt, 768, 768);
  transpose_cast<<<dim3(32, 24), tblk, 0, stream>>>(head_w, hwt, 768, 1000);
  patch_ln1<<<PROWS, blk, 0, stream>>>(img, p_ln1_g, p_ln1_b, xpb);
  gemm_v2<0, 0, 0><<<dim3(6, 98), blk, 0, stream>>>(xpb, pwt, patch_b, nullptr, xe,
                                                    PROWS, 768, 768);
  ln2_pos<<<PROWS, blk, 0, stream>>>(xe, p_ln2_g, p_ln2_b, pos_emb, x);
  cls_init<<<B_, blk, 0, stream>>>(cls_tok, pos_emb, x);

  for (int l = 0; l < NL; ++l) {
    transpose4<<<6912, tblk, 0, stream>>>(w_qkv + (size_t)l * 768 * 2304,
                                          w_out + (size_t)l * 768 * 768,
                                          ff_w1 + (size_t)l * 768 * MFF,
                                          ff_w2 + (size_t)l * MFF * 768,
                                          wtq, wto, wt1, wt2);

    ln_rows_b<<<ROWS, blk, 0, stream>>>(x, 768, attn_ln_g + (size_t)l * 768,
                                        attn_ln_b + (size_t)l * 768, xnb);
    gemm_v2<0, 0, 1><<<dim3(18, 99), blk, 0, stream>>>(xnb, wtq, nullptr, nullptr, qkvb,
                                                       ROWS, 2304, 768);
    attn_mfma<<<B_ * NH * 4, blk, 0, stream>>>(qkvb, aoutb);
    gemm_v2<0, 1, 0><<<dim3(6, 99), blk, 0, stream>>>(aoutb, wto, b_out + (size_t)l * 768,
                                                      x, x, ROWS, 768, 768);
    ln_rows_b<<<ROWS, blk, 0, stream>>>(x, 768, ff_ln_g + (size_t)l * 768,
                                        ff_ln_b + (size_t)l * 768, xnb);
    gemm_v2<1, 0, 1><<<dim3(24, 99), blk, 0, stream>>>(xnb, wt1, ff_b1 + (size_t)l * MFF,
                                                       nullptr, hidb, ROWS, MFF, 768);
    gemm_v2<0, 1, 0><<<dim3(6, 99), blk, 0, stream>>>(hidb, wt2, ff_b2 + (size_t)l * 768,
                                                      x, x, ROWS, 768, MFF);
  }

  // ---- final LN (cls rows) + head ----
  ln_rows_b<<<B_, blk, 0, stream>>>(x, (long)NTOK * 768, fin_ln_g, fin_ln_b, xclsb);
  gemm_bt<0, 0, 0><<<dim3(8, 1), blk, 0, stream>>>(xclsb, hwt, head_b, nullptr, out,
                                                   B_, NCLS, 768);
}

// Round 6
// 4545.652 us; speedup vs baseline: 1.5131x; 1.2493x over previous
//
#include <hip/hip_runtime.h>
#include <hip/hip_bf16.h>
#include <math.h>

// ---- problem constants ----
#define B_     64
#define NTOK   197
#define NPATCH 196
#define D768   768
#define NL     12
#define NH     12
#define MFF    3072
#define NCLS   1000
#define ROWS   (B_ * NTOK)      // 12608
#define PROWS  (B_ * NPATCH)    // 12544
#define ROWS_PAD 12672          // 99 * 128

typedef unsigned short ushort;
typedef __bf16 bf16x8 __attribute__((ext_vector_type(8)));
typedef float  f32x4  __attribute__((ext_vector_type(4)));
typedef unsigned short u16x4 __attribute__((ext_vector_type(4)));

__device__ __forceinline__ ushort f2b(float f) {
  __hip_bfloat16 h = __float2bfloat16(f);
  return *reinterpret_cast<ushort*>(&h);
}

__device__ __forceinline__ void gload16(const ushort* g, ushort* lds) {
  __builtin_amdgcn_global_load_lds((const __attribute__((address_space(1))) void*)g,
                                   (__attribute__((address_space(3))) void*)lds, 16, 0, 0);
}

// ---------------- block-wide mean/rstd over 768 elems (256 threads) ----------------
__device__ __forceinline__ void block_mean_rstd(float s, float sq, float& mean, float& rstd) {
#pragma unroll
  for (int off = 32; off; off >>= 1) { s += __shfl_xor(s, off); sq += __shfl_xor(sq, off); }
  __shared__ float ss[4], ssq[4];
  int w = threadIdx.x >> 6;
  if ((threadIdx.x & 63) == 0) { ss[w] = s; ssq[w] = sq; }
  __syncthreads();
  s  = ss[0] + ss[1] + ss[2] + ss[3];
  sq = ssq[0] + ssq[1] + ssq[2] + ssq[3];
  mean = s * (1.0f / 768.0f);
  float var = sq * (1.0f / 768.0f) - mean * mean;
  rstd = rsqrtf(var + 1e-5f);
}

// ---------------- LN over rows of 768 (fp32 in, bf16 out) ----------------
__global__ __launch_bounds__(256) void ln_rows_b(const float* __restrict__ in, long in_stride,
                                                 const float* __restrict__ g,
                                                 const float* __restrict__ bta,
                                                 ushort* __restrict__ out) {
  const float* xr = in + (size_t)blockIdx.x * in_stride;
  int t = threadIdx.x;
  float v0 = xr[t], v1 = xr[t + 256], v2 = xr[t + 512];
  float mean, rstd;
  block_mean_rstd(v0 + v1 + v2, v0 * v0 + v1 * v1 + v2 * v2, mean, rstd);
  ushort* o = out + (size_t)blockIdx.x * 768;
  o[t]       = f2b((v0 - mean) * rstd * g[t]       + bta[t]);
  o[t + 256] = f2b((v1 - mean) * rstd * g[t + 256] + bta[t + 256]);
  o[t + 512] = f2b((v2 - mean) * rstd * g[t + 512] + bta[t + 512]);
}

// ---------------- patch extraction + LN1 (bf16 out) ----------------
__global__ __launch_bounds__(256) void patch_ln1(const float* __restrict__ img,
                                                 const float* __restrict__ g,
                                                 const float* __restrict__ bta,
                                                 ushort* __restrict__ xp) {
  int pidx = blockIdx.x;                 // b*196 + ph*14 + pw
  int b = pidx / NPATCH, hw = pidx % NPATCH;
  int ph = hw / 14, pw = hw % 14;
  int t = threadIdx.x;
  float v[3];
#pragma unroll
  for (int u = 0; u < 3; ++u) {
    int k = t + u * 256;                  // feature index (p1*16+p2)*3 + c
    int c = k % 3, p2 = (k / 3) & 15, p1 = k / 48;
    v[u] = img[(((size_t)b * 3 + c) * 224 + ph * 16 + p1) * 224 + pw * 16 + p2];
  }
  float mean, rstd;
  block_mean_rstd(v[0] + v[1] + v[2], v[0] * v[0] + v[1] * v[1] + v[2] * v[2], mean, rstd);
  ushort* o = xp + (size_t)pidx * 768;
#pragma unroll
  for (int u = 0; u < 3; ++u) { int k = t + u * 256; o[k] = f2b((v[u] - mean) * rstd * g[k] + bta[k]); }
}

// ---------------- LN2 + pos_emb, scatter into x at token 1+i (fp32) ----------------
__global__ __launch_bounds__(256) void ln2_pos(const float* __restrict__ xe,
                                               const float* __restrict__ g,
                                               const float* __restrict__ bta,
                                               const float* __restrict__ pos,
                                               float* __restrict__ x) {
  int pidx = blockIdx.x;
  int b = pidx / NPATCH, i = pidx % NPATCH;
  const float* xr = xe + (size_t)pidx * 768;
  int t = threadIdx.x;
  float v0 = xr[t], v1 = xr[t + 256], v2 = xr[t + 512];
  float mean, rstd;
  block_mean_rstd(v0 + v1 + v2, v0 * v0 + v1 * v1 + v2 * v2, mean, rstd);
  const float* p = pos + (size_t)(1 + i) * 768;
  float* o = x + ((size_t)b * NTOK + 1 + i) * 768;
  o[t]       = (v0 - mean) * rstd * g[t]       + bta[t]       + p[t];
  o[t + 256] = (v1 - mean) * rstd * g[t + 256] + bta[t + 256] + p[t + 256];
  o[t + 512] = (v2 - mean) * rstd * g[t + 512] + bta[t + 512] + p[t + 512];
}

// ---------------- cls token + pos_emb[0] ----------------
__global__ __launch_bounds__(256) void cls_init(const float* __restrict__ cls_tok,
                                                const float* __restrict__ pos,
                                                float* __restrict__ x) {
  int b = blockIdx.x, t = threadIdx.x;
  float* o = x + (size_t)b * NTOK * 768;
#pragma unroll
  for (int u = 0; u < 3; ++u) { int k = t + u * 256; o[k] = cls_tok[k] + pos[k]; }
}

// ---------------- cast + transpose: W fp32 [K][N] -> Wt bf16 [N][K] (bounds-checked) ----------------
__global__ __launch_bounds__(256) void transpose_cast(const float* __restrict__ W,
                                                      ushort* __restrict__ Wt,
                                                      int K, int N) {
  __shared__ float t[32][33];
  int n0 = blockIdx.x * 32, k0 = blockIdx.y * 32;
  int tx = threadIdx.x, ty = threadIdx.y;   // 32 x 8
#pragma unroll
  for (int u = 0; u < 32; u += 8) {
    int n = n0 + tx;
    t[ty + u][tx] = (n < N) ? W[(size_t)(k0 + ty + u) * N + n] : 0.f;
  }
  __syncthreads();
#pragma unroll
  for (int u = 0; u < 32; u += 8) {
    int n = n0 + ty + u;
    if (n < N) Wt[(size_t)n * K + k0 + tx] = f2b(t[tx][ty + u]);
  }
}

// ---------------- merged per-layer transposes (all dims %32==0, no bounds) ----------------
__global__ __launch_bounds__(256) void transpose4(const float* __restrict__ wq,
                                                  const float* __restrict__ wo,
                                                  const float* __restrict__ w1,
                                                  const float* __restrict__ w2,
                                                  ushort* __restrict__ tq,
                                                  ushort* __restrict__ to,
                                                  ushort* __restrict__ t1,
                                                  ushort* __restrict__ t2) {
  int bid = blockIdx.x;
  const float* W; ushort* Wt; int K, N, xt;
  if (bid < 1728)      {             W = wq; Wt = tq; K = 768;  N = 2304; xt = 72; }
  else if (bid < 2304) { bid -= 1728; W = wo; Wt = to; K = 768;  N = 768;  xt = 24; }
  else if (bid < 4608) { bid -= 2304; W = w1; Wt = t1; K = 768;  N = 3072; xt = 96; }
  else                 { bid -= 4608; W = w2; Wt = t2; K = 3072; N = 768;  xt = 24; }
  int n0 = (bid % xt) * 32, k0 = (bid / xt) * 32;
  __shared__ float t[32][33];
  int tx = threadIdx.x, ty = threadIdx.y;   // 32 x 8
#pragma unroll
  for (int u = 0; u < 32; u += 8)
    t[ty + u][tx] = W[(size_t)(k0 + ty + u) * N + n0 + tx];
  __syncthreads();
#pragma unroll
  for (int u = 0; u < 32; u += 8)
    Wt[(size_t)(n0 + ty + u) * K + k0 + tx] = f2b(t[tx][ty + u]);
}

// ================= bf16 MFMA GEMM v3: 2-phase double-buffered =================
// A [M][K] bf16, Bt [N][K] bf16 row-major. K % 64 == 0, N % 128 == 0. Tile 128x128,
// BK=64, 256 thr / 4 waves (2x2). Swapped-operand MFMA (lane holds 4 contiguous
// output cols). 2-phase schedule (catalog T3-minimum): per iter issue next-tile
// global_load_lds into buf^1 FIRST, then ds_read+32xMFMA on buf, then one
// vmcnt(0)+s_barrier. XCD-chunked bijective block swizzle (m204): logical tiles
// are x-major so one row-panel's col-tiles land on one XCD -> A fetched ~once.
template<int EP, int RESID, int OBF>
__global__ __launch_bounds__(256) void gemm_v3(const ushort* __restrict__ A,
                                               const ushort* __restrict__ Bt,
                                               const float* __restrict__ bias,
                                               const float* __restrict__ resid,
                                               void* __restrict__ Cv,
                                               int M, int N, int K) {
  __shared__ ushort smem[2 * 16384];        // 2 bufs x (As 8192 + Bs 8192) = 64 KB

  const int tid = threadIdx.x;
  const int w = tid >> 6, l = tid & 63;
  const int fr = l & 15, fc = l >> 4;

  // bijective XCD-aware swizzle (m204)
  const int ntx = gridDim.x;
  const int nwg = ntx * gridDim.y;
  const int orig = blockIdx.y * ntx + blockIdx.x;
  const int q = nwg >> 3, r = nwg & 7, xcd = orig & 7, idx = orig >> 3;
  const int wg = (xcd < r ? xcd * (q + 1) : r * (q + 1) + (xcd - r) * q) + idx;
  const int row0 = (wg / ntx) * 128, col0 = (wg % ntx) * 128;

  const int wr = (w >> 1) * 64, wc = (w & 1) * 64;

  // staging coords: chunk c = i*256 + w*64 + l -> row c>>3, slot c&7 holds
  // global chunk (c&7)^((c>>3)&7); per-thread global base precomputed.
  const int srow = w * 8 + (l >> 3);
  const int sg = (l & 7) ^ (l >> 3);
  const ushort* pA[4]; const ushort* pB[4];
#pragma unroll
  for (int i = 0; i < 4; ++i) {
    pA[i] = A  + (size_t)(row0 + i * 32 + srow) * K + sg * 8;
    pB[i] = Bt + (size_t)(col0 + i * 32 + srow) * K + sg * 8;
  }

  auto stage = [&](int k0, int buf) {
    ushort* As = smem + buf * 16384;
    ushort* Bs = As + 8192;
#pragma unroll
    for (int i = 0; i < 4; ++i) {
      gload16(pA[i] + k0, As + (i * 256 + w * 64) * 8);
      gload16(pB[i] + k0, Bs + (i * 256 + w * 64) * 8);
    }
  };

  f32x4 acc[4][4] = {};
  const int nIter = K >> 6;

  // prologue
  stage(0, 0);
  asm volatile("s_waitcnt vmcnt(0)" ::: "memory");
  __builtin_amdgcn_s_barrier();

  int buf = 0;
  for (int t = 0; t < nIter; ++t) {
    if (t + 1 < nIter) stage((t + 1) * 64, buf ^ 1);   // issue BEFORE compute
    const ushort* As = smem + buf * 16384;
    const ushort* Bs = As + 8192;
#pragma unroll
    for (int ks = 0; ks < 2; ++ks) {
      const int sw = ((ks * 4 + fc) ^ (fr & 7)) << 3;
      bf16x8 a_[4], b_[4];
#pragma unroll
      for (int m = 0; m < 4; ++m)
        a_[m] = *(const bf16x8*)(As + (wr + m * 16 + fr) * 64 + sw);
#pragma unroll
      for (int n = 0; n < 4; ++n)
        b_[n] = *(const bf16x8*)(Bs + (wc + n * 16 + fr) * 64 + sw);
#pragma unroll
      for (int m = 0; m < 4; ++m)
#pragma unroll
        for (int n = 0; n < 4; ++n)
          acc[m][n] = __builtin_amdgcn_mfma_f32_16x16x32_bf16(b_[n], a_[m], acc[m][n], 0, 0, 0);
    }
    asm volatile("s_waitcnt vmcnt(0)" ::: "memory");   // next tile landed
    __builtin_amdgcn_s_barrier();
    buf ^= 1;
  }

  if (!OBF) {
    // fp32 output: dwordx4 bias/resid/store (64B row segments)
    float* Cf = (float*)Cv;
#pragma unroll
    for (int m = 0; m < 4; ++m) {
      int row = row0 + wr + m * 16 + fr;
      if (row >= M) continue;
#pragma unroll
      for (int n = 0; n < 4; ++n) {
        int col = col0 + wc + n * 16 + fc * 4;
        f32x4 v = acc[m][n];
        if (bias) v += *(const f32x4*)(bias + col);
        if (EP) {
#pragma unroll
          for (int rr = 0; rr < 4; ++rr)
            v[rr] = 0.5f * v[rr] * (1.0f + erff(v[rr] * 0.70710678118654752f));
        }
        if (RESID) v += *(const f32x4*)(resid + (size_t)row * N + col);
        *(f32x4*)(Cf + (size_t)row * N + col) = v;
      }
    }
  } else {
    // bf16 output: per-wave LDS restage -> ushort4 stores (128B rows)
    ushort* Cw = smem + w * 4096;
#pragma unroll
    for (int m = 0; m < 4; ++m) {
      int rl = m * 16 + fr;
#pragma unroll
      for (int n = 0; n < 4; ++n) {
        int col = col0 + wc + n * 16 + fc * 4;
        f32x4 v = acc[m][n];
        if (bias) v += *(const f32x4*)(bias + col);
        if (EP) {
#pragma unroll
          for (int rr = 0; rr < 4; ++rr)
            v[rr] = 0.5f * v[rr] * (1.0f + erff(v[rr] * 0.70710678118654752f));
        }
        u16x4 pk = { f2b(v[0]), f2b(v[1]), f2b(v[2]), f2b(v[3]) };
        int s = (n * 4 + fc) ^ (rl & 7);
        *(u16x4*)(Cw + rl * 64 + s * 4) = pk;
      }
    }
    ushort* Cb = (ushort*)Cv;
#pragma unroll
    for (int pp = 0; pp < 16; ++pp) {
      int rl = pp * 4 + (l >> 4);
      int cs = l & 15;
      u16x4 pk = *(const u16x4*)(Cw + rl * 64 + ((cs ^ (rl & 7)) * 4));
      int row = row0 + wr + rl;
      if (row < M) *(u16x4*)(Cb + (size_t)row * N + col0 + wc + cs * 4) = pk;
    }
  }
}

// ---------------- 128x128 bf16 MFMA GEMM (head only, N-bounds-safe) ----------------
template<int EP, int RESID, int OBF>
__global__ __launch_bounds__(256) void gemm_bt(const ushort* __restrict__ A,
                                               const ushort* __restrict__ Bt,
                                               const float* __restrict__ bias,
                                               const float* __restrict__ resid,
                                               void* __restrict__ C,
                                               int M, int N, int K) {
  __shared__ ushort As[128 * 32];
  __shared__ ushort Bs[128 * 32];
  int tid = threadIdx.x;
  int w = tid >> 6, l = tid & 63;
  int fr = l & 15, fc = l >> 4;
  int row0 = blockIdx.y * 128, col0 = blockIdx.x * 128;
  int wr = (w >> 1) * 64, wc = (w & 1) * 64;

  int srow0 = w * 32 + (l >> 2);
  int srow1 = srow0 + 16;
  int sc0 = (((l & 3) ^ ((srow0 >> 1) & 3)) << 3);
  int sc1 = (((l & 3) ^ ((srow1 >> 1) & 3)) << 3);
  const ushort* ga0 = A  + (size_t)(row0 + srow0) * K + sc0;
  const ushort* ga1 = A  + (size_t)(row0 + srow1) * K + sc1;
  const ushort* gb0 = Bt + (size_t)(col0 + srow0) * K + sc0;
  const ushort* gb1 = Bt + (size_t)(col0 + srow1) * K + sc1;

  int idxA[4], idxB[4];
#pragma unroll
  for (int m = 0; m < 4; ++m) {
    int rA = wr + m * 16 + fr;
    idxA[m] = rA * 32 + ((fc ^ ((rA >> 1) & 3)) << 3);
  }
#pragma unroll
  for (int n = 0; n < 4; ++n) {
    int rB = wc + n * 16 + fr;
    idxB[n] = rB * 32 + ((fc ^ ((rB >> 1) & 3)) << 3);
  }

  f32x4 acc[4][4] = {};

  for (int k0 = 0; k0 < K; k0 += 32) {
    gload16(ga0 + k0, &As[w * 1024]);
    gload16(ga1 + k0, &As[w * 1024 + 512]);
    gload16(gb0 + k0, &Bs[w * 1024]);
    gload16(gb1 + k0, &Bs[w * 1024 + 512]);
    __syncthreads();
    bf16x8 af[4], bfr[4];
#pragma unroll
    for (int m = 0; m < 4; ++m) af[m] = *(const bf16x8*)(As + idxA[m]);
#pragma unroll
    for (int n = 0; n < 4; ++n) bfr[n] = *(const bf16x8*)(Bs + idxB[n]);
#pragma unroll
    for (int m = 0; m < 4; ++m)
#pragma unroll
      for (int n = 0; n < 4; ++n)
        acc[m][n] = __builtin_amdgcn_mfma_f32_16x16x32_bf16(af[m], bfr[n], acc[m][n], 0, 0, 0);
    __syncthreads();
  }

#pragma unroll
  for (int n = 0; n < 4; ++n) {
    int col = col0 + wc + n * 16 + fr;
    if (col >= N) continue;
    float bv = bias ? bias[col] : 0.f;
#pragma unroll
    for (int m = 0; m < 4; ++m) {
#pragma unroll
      for (int rr = 0; rr < 4; ++rr) {
        int row = row0 + wr + m * 16 + fc * 4 + rr;
        if (row >= M) continue;
        float v = acc[m][n][rr] + bv;
        if (EP == 1) v = 0.5f * v * (1.0f + erff(v * 0.70710678118654752f));
        if (RESID) v += resid[(size_t)row * N + col];
        if (OBF) ((ushort*)C)[(size_t)row * N + col] = f2b(v);
        else     ((float*)C)[(size_t)row * N + col]  = v;
      }
    }
  }
}

// ---------------- MFMA flash attention ----------------
__global__ __launch_bounds__(256) void attn_mfma(const ushort* __restrict__ qkv,
                                                 ushort* __restrict__ aout) {
  int bid = blockIdx.x;
  int qt = bid & 3;
  int h  = (bid >> 2) % NH;
  int b  = (bid >> 2) / NH;
  int tid = threadIdx.x, w = tid >> 6, l = tid & 63;
  int fr = l & 15, fc = l >> 4;

  __shared__ ushort Vt[64 * 64];        // swizzled V^T tile [d][key]
  __shared__ ushort Pl[4 * 16 * 64];    // per-wave P [qrow][key], swizzled

  const size_t brow = (size_t)b * NTOK;
  int q0 = qt * 64 + w * 16;

  bf16x8 qf[2];
  {
    const ushort* qp = qkv + (brow + q0 + fr) * 2304 + h * 64 + fc * 8;
    qf[0] = *(const bf16x8*)qp;
    qf[1] = *(const bf16x8*)(qp + 32);
  }
  float rs[4] = {0.f, 0.f, 0.f, 0.f};
  f32x4 oc[4] = {};

  for (int kt = 0; kt < 4; ++kt) {
    __syncthreads();
    {
      int key = tid >> 2, d0 = (tid & 3) * 16;
      int j = kt * 64 + key;
      bool valid = j < NTOK;
      const ushort* vp = qkv + (brow + j) * 2304 + 1536 + h * 64 + d0;
      ushort vbuf[16];
      if (valid) {
        *(bf16x8*)(vbuf)     = *(const bf16x8*)vp;
        *(bf16x8*)(vbuf + 8) = *(const bf16x8*)(vp + 8);
      } else {
#pragma unroll
        for (int i = 0; i < 16; ++i) vbuf[i] = 0;
      }
#pragma unroll
      for (int i = 0; i < 16; ++i) {
        int d = d0 + i;
        int byte = d * 128 + ((((key >> 3)) ^ (d & 7)) << 4) + (key & 7) * 2;
        Vt[byte >> 1] = vbuf[i];
      }
    }
    f32x4 sc[4];
#pragma unroll
    for (int n = 0; n < 4; ++n) {
      f32x4 z = {};
      const ushort* kp = qkv + (brow + kt * 64 + n * 16 + fr) * 2304 + 768 + h * 64 + fc * 8;
      bf16x8 k0 = *(const bf16x8*)kp;
      bf16x8 k1 = *(const bf16x8*)(kp + 32);
      z = __builtin_amdgcn_mfma_f32_16x16x32_bf16(qf[0], k0, z, 0, 0, 0);
      z = __builtin_amdgcn_mfma_f32_16x16x32_bf16(qf[1], k1, z, 0, 0, 0);
      sc[n] = z;
    }
    float part[4] = {0.f, 0.f, 0.f, 0.f};
#pragma unroll
    for (int n = 0; n < 4; ++n) {
      int j = kt * 64 + n * 16 + fr;
      bool jv = j < NTOK;
#pragma unroll
      for (int rr = 0; rr < 4; ++rr) {
        float e = jv ? __expf(sc[n][rr] * 0.125f) : 0.f;
        part[rr] += e;
        int row = fc * 4 + rr, col = n * 16 + fr;
        int byte = row * 128 + (((col >> 3) ^ (row & 7)) << 4) + (col & 7) * 2;
        Pl[w * 1024 + (byte >> 1)] = f2b(e);
      }
    }
#pragma unroll
    for (int rr = 0; rr < 4; ++rr) {
      float p = part[rr];
      p += __shfl_xor(p, 1); p += __shfl_xor(p, 2);
      p += __shfl_xor(p, 4); p += __shfl_xor(p, 8);
      rs[rr] += p;
    }
    __syncthreads();
#pragma unroll
    for (int ks = 0; ks < 2; ++ks) {
      int prow = fr;
      int pbyte = prow * 128 + (((ks * 4 + fc) ^ (prow & 7)) << 4);
      bf16x8 pf = *(const bf16x8*)(Pl + w * 1024 + (pbyte >> 1));
#pragma unroll
      for (int n = 0; n < 4; ++n) {
        int d = n * 16 + fr;
        int vb = d * 128 + (((ks * 4 + fc) ^ (d & 7)) << 4);
        bf16x8 vf = *(const bf16x8*)(Vt + (vb >> 1));
        oc[n] = __builtin_amdgcn_mfma_f32_16x16x32_bf16(pf, vf, oc[n], 0, 0, 0);
      }
    }
  }
#pragma unroll
  for (int n = 0; n < 4; ++n) {
#pragma unroll
    for (int rr = 0; rr < 4; ++rr) {
      int qq = q0 + fc * 4 + rr;
      if (qq < NTOK) {
        float v = oc[n][rr] / (rs[rr] + 1e-8f);
        aout[(brow + qq) * 768 + h * 64 + n * 16 + fr] = f2b(v);
      }
    }
  }
}

// ---------------- host launch ----------------
extern "C" void kernel_launch(void* const* d_in, const int* in_sizes, int n_in,
                              void* d_out, int out_size, void* d_ws, size_t ws_size,
                              hipStream_t stream) {
  const float* img       = (const float*)d_in[0];
  const float* p_ln1_g   = (const float*)d_in[1];
  const float* p_ln1_b   = (const float*)d_in[2];
  const float* patch_w   = (const float*)d_in[3];
  const float* patch_b   = (const float*)d_in[4];
  const float* p_ln2_g   = (const float*)d_in[5];
  const float* p_ln2_b   = (const float*)d_in[6];
  const float* pos_emb   = (const float*)d_in[7];
  const float* cls_tok   = (const float*)d_in[8];
  const float* attn_ln_g = (const float*)d_in[9];
  const float* attn_ln_b = (const float*)d_in[10];
  const float* w_qkv     = (const float*)d_in[11];
  const float* w_out     = (const float*)d_in[12];
  const float* b_out     = (const float*)d_in[13];
  const float* ff_ln_g   = (const float*)d_in[14];
  const float* ff_ln_b   = (const float*)d_in[15];
  const float* ff_w1     = (const float*)d_in[16];
  const float* ff_b1     = (const float*)d_in[17];
  const float* ff_w2     = (const float*)d_in[18];
  const float* ff_b2     = (const float*)d_in[19];
  const float* fin_ln_g  = (const float*)d_in[20];
  const float* fin_ln_b  = (const float*)d_in[21];
  const float* head_w    = (const float*)d_in[22];
  const float* head_b    = (const float*)d_in[23];
  float* out = (float*)d_out;

  // ---- workspace carve ----
  char* p = (char*)d_ws;
  auto alloc = [&](size_t bytes) { char* r = p; p += (bytes + 255) & ~(size_t)255; return r; };
  float*  x      = (float*) alloc((size_t)ROWS_PAD * 768 * 4);
  ushort* xnb    = (ushort*)alloc((size_t)ROWS_PAD * 768 * 2);
  ushort* qkvb   = (ushort*)alloc((size_t)ROWS_PAD * 2304 * 2);
  ushort* aoutb  = (ushort*)alloc((size_t)ROWS_PAD * 768 * 2);
  ushort* wtq    = (ushort*)alloc((size_t)2304 * 768 * 2);
  ushort* wto    = (ushort*)alloc((size_t)768 * 768 * 2);
  ushort* wt1    = (ushort*)alloc((size_t)3072 * 768 * 2);
  ushort* wt2    = (ushort*)alloc((size_t)768 * 3072 * 2);
  ushort* pwt    = (ushort*)alloc((size_t)768 * 768 * 2);
  ushort* hwt    = (ushort*)alloc((size_t)1024 * 768 * 2);
  ushort* xclsb  = (ushort*)alloc((size_t)128 * 768 * 2);
  ushort* hidb   = qkvb;                 // [ROWS_PAD][3072] aliases qkvb+aoutb
  ushort* xpb    = xnb;                  // patch LN1 out (12544 rows)
  float*  xe     = (float*)qkvb;         // patch GEMM out fp32 (pre-loop only)

  dim3 blk(256), tblk(32, 8);

  // ---- patch embedding ----
  transpose_cast<<<dim3(24, 24), tblk, 0, stream>>>(patch_w, pwt, 768, 768);
  transpose_cast<<<dim3(32, 24), tblk, 0, stream>>>(head_w, hwt, 768, 1000);
  patch_ln1<<<PROWS, blk, 0, stream>>>(img, p_ln1_g, p_ln1_b, xpb);
  gemm_v3<0, 0, 0><<<dim3(6, 98), blk, 0, stream>>>(xpb, pwt, patch_b, nullptr, xe,
                                                    PROWS, 768, 768);
  ln2_pos<<<PROWS, blk, 0, stream>>>(xe, p_ln2_g, p_ln2_b, pos_emb, x);
  cls_init<<<B_, blk, 0, stream>>>(cls_tok, pos_emb, x);

  for (int l = 0; l < NL; ++l) {
    transpose4<<<6912, tblk, 0, stream>>>(w_qkv + (size_t)l * 768 * 2304,
                                          w_out + (size_t)l * 768 * 768,
                                          ff_w1 + (size_t)l * 768 * MFF,
                                          ff_w2 + (size_t)l * MFF * 768,
                                          wtq, wto, wt1, wt2);

    ln_rows_b<<<ROWS, blk, 0, stream>>>(x, 768, attn_ln_g + (size_t)l * 768,
                                        attn_ln_b + (size_t)l * 768, xnb);
    gemm_v3<0, 0, 1><<<dim3(18, 99), blk, 0, stream>>>(xnb, wtq, nullptr, nullptr, qkvb,
                                                       ROWS, 2304, 768);
    attn_mfma<<<B_ * NH * 4, blk, 0, stream>>>(qkvb, aoutb);
    gemm_v3<0, 1, 0><<<dim3(6, 99), blk, 0, stream>>>(aoutb, wto, b_out + (size_t)l * 768,
                                                      x, x, ROWS, 768, 768);
    ln_rows_b<<<ROWS, blk, 0, stream>>>(x, 768, ff_ln_g + (size_t)l * 768,
                                        ff_ln_b + (size_t)l * 768, xnb);
    gemm_v3<1, 0, 1><<<dim3(24, 99), blk, 0, stream>>>(xnb, wt1, ff_b1 + (size_t)l * MFF,
                                                       nullptr, hidb, ROWS, MFF, 768);
    gemm_v3<0, 1, 0><<<dim3(6, 99), blk, 0, stream>>>(hidb, wt2, ff_b2 + (size_t)l * 768,
                                                      x, x, ROWS, 768, MFF);
  }

  // ---- final LN (cls rows) + head ----
  ln_rows_b<<<B_, blk, 0, stream>>>(x, (long)NTOK * 768, fin_ln_g, fin_ln_b, xclsb);
  gemm_bt<0, 0, 0><<<dim3(8, 1), blk, 0, stream>>>(xclsb, hwt, head_b, nullptr, out,
                                                   B_, NCLS, 768);
}

// Round 8
// 4423.903 us; speedup vs baseline: 1.5547x; 1.0275x over previous
//
#include <hip/hip_runtime.h>
#include <hip/hip_bf16.h>
#include <math.h>

// ---- problem constants ----
#define B_     64
#define NTOK   197
#define NPATCH 196
#define D768   768
#define NL     12
#define NH     12
#define MFF    3072
#define NCLS   1000
#define ROWS   (B_ * NTOK)      // 12608
#define PROWS  (B_ * NPATCH)    // 12544
#define ROWS_PAD 12672          // 99 * 128

typedef unsigned short ushort;
typedef __bf16 bf16x8 __attribute__((ext_vector_type(8)));
typedef float  f32x4  __attribute__((ext_vector_type(4)));
typedef unsigned short u16x4 __attribute__((ext_vector_type(4)));

__device__ __forceinline__ ushort f2b(float f) {
  __hip_bfloat16 h = __float2bfloat16(f);
  return *reinterpret_cast<ushort*>(&h);
}

__device__ __forceinline__ void gload16(const ushort* g, ushort* lds) {
  __builtin_amdgcn_global_load_lds((const __attribute__((address_space(1))) void*)g,
                                   (__attribute__((address_space(3))) void*)lds, 16, 0, 0);
}

// tanh-form GELU via exp (max err ~1e-3, < bf16 quantization at those magnitudes)
__device__ __forceinline__ float gelu_f(float v) {
  float t = v * fmaf(0.0713548162726f, v * v, 1.5957691216f);
  return v / (1.0f + __expf(-t));
}

// ---------------- block-wide mean/rstd over 768 elems (256 threads) ----------------
__device__ __forceinline__ void block_mean_rstd(float s, float sq, float& mean, float& rstd) {
#pragma unroll
  for (int off = 32; off; off >>= 1) { s += __shfl_xor(s, off); sq += __shfl_xor(sq, off); }
  __shared__ float ss[4], ssq[4];
  int w = threadIdx.x >> 6;
  if ((threadIdx.x & 63) == 0) { ss[w] = s; ssq[w] = sq; }
  __syncthreads();
  s  = ss[0] + ss[1] + ss[2] + ss[3];
  sq = ssq[0] + ssq[1] + ssq[2] + ssq[3];
  mean = s * (1.0f / 768.0f);
  float var = sq * (1.0f / 768.0f) - mean * mean;
  rstd = rsqrtf(var + 1e-5f);
}

// ---------------- LN over rows of 768 (fp32 in, bf16 out) ----------------
__global__ __launch_bounds__(256) void ln_rows_b(const float* __restrict__ in, long in_stride,
                                                 const float* __restrict__ g,
                                                 const float* __restrict__ bta,
                                                 ushort* __restrict__ out) {
  const float* xr = in + (size_t)blockIdx.x * in_stride;
  int t = threadIdx.x;
  float v0 = xr[t], v1 = xr[t + 256], v2 = xr[t + 512];
  float mean, rstd;
  block_mean_rstd(v0 + v1 + v2, v0 * v0 + v1 * v1 + v2 * v2, mean, rstd);
  ushort* o = out + (size_t)blockIdx.x * 768;
  o[t]       = f2b((v0 - mean) * rstd * g[t]       + bta[t]);
  o[t + 256] = f2b((v1 - mean) * rstd * g[t + 256] + bta[t + 256]);
  o[t + 512] = f2b((v2 - mean) * rstd * g[t + 512] + bta[t + 512]);
}

// ---------------- patch extraction + LN1 (bf16 out) ----------------
__global__ __launch_bounds__(256) void patch_ln1(const float* __restrict__ img,
                                                 const float* __restrict__ g,
                                                 const float* __restrict__ bta,
                                                 ushort* __restrict__ xp) {
  int pidx = blockIdx.x;                 // b*196 + ph*14 + pw
  int b = pidx / NPATCH, hw = pidx % NPATCH;
  int ph = hw / 14, pw = hw % 14;
  int t = threadIdx.x;
  float v[3];
#pragma unroll
  for (int u = 0; u < 3; ++u) {
    int k = t + u * 256;                  // feature index (p1*16+p2)*3 + c
    int c = k % 3, p2 = (k / 3) & 15, p1 = k / 48;
    v[u] = img[(((size_t)b * 3 + c) * 224 + ph * 16 + p1) * 224 + pw * 16 + p2];
  }
  float mean, rstd;
  block_mean_rstd(v[0] + v[1] + v[2], v[0] * v[0] + v[1] * v[1] + v[2] * v[2], mean, rstd);
  ushort* o = xp + (size_t)pidx * 768;
#pragma unroll
  for (int u = 0; u < 3; ++u) { int k = t + u * 256; o[k] = f2b((v[u] - mean) * rstd * g[k] + bta[k]); }
}

// ---------------- LN2 + pos_emb, scatter into x at token 1+i (fp32) ----------------
__global__ __launch_bounds__(256) void ln2_pos(const float* __restrict__ xe,
                                               const float* __restrict__ g,
                                               const float* __restrict__ bta,
                                               const float* __restrict__ pos,
                                               float* __restrict__ x) {
  int pidx = blockIdx.x;
  int b = pidx / NPATCH, i = pidx % NPATCH;
  const float* xr = xe + (size_t)pidx * 768;
  int t = threadIdx.x;
  float v0 = xr[t], v1 = xr[t + 256], v2 = xr[t + 512];
  float mean, rstd;
  block_mean_rstd(v0 + v1 + v2, v0 * v0 + v1 * v1 + v2 * v2, mean, rstd);
  const float* p = pos + (size_t)(1 + i) * 768;
  float* o = x + ((size_t)b * NTOK + 1 + i) * 768;
  o[t]       = (v0 - mean) * rstd * g[t]       + bta[t]       + p[t];
  o[t + 256] = (v1 - mean) * rstd * g[t + 256] + bta[t + 256] + p[t + 256];
  o[t + 512] = (v2 - mean) * rstd * g[t + 512] + bta[t + 512] + p[t + 512];
}

// ---------------- cls token + pos_emb[0] ----------------
__global__ __launch_bounds__(256) void cls_init(const float* __restrict__ cls_tok,
                                                const float* __restrict__ pos,
                                                float* __restrict__ x) {
  int b = blockIdx.x, t = threadIdx.x;
  float* o = x + (size_t)b * NTOK * 768;
#pragma unroll
  for (int u = 0; u < 3; ++u) { int k = t + u * 256; o[k] = cls_tok[k] + pos[k]; }
}

// ---------------- cast + transpose: W fp32 [K][N] -> Wt bf16 [N][K] (bounds-checked) ----------------
__global__ __launch_bounds__(256) void transpose_cast(const float* __restrict__ W,
                                                      ushort* __restrict__ Wt,
                                                      int K, int N) {
  __shared__ float t[32][33];
  int n0 = blockIdx.x * 32, k0 = blockIdx.y * 32;
  int tx = threadIdx.x, ty = threadIdx.y;   // 32 x 8
#pragma unroll
  for (int u = 0; u < 32; u += 8) {
    int n = n0 + tx;
    t[ty + u][tx] = (n < N) ? W[(size_t)(k0 + ty + u) * N + n] : 0.f;
  }
  __syncthreads();
#pragma unroll
  for (int u = 0; u < 32; u += 8) {
    int n = n0 + ty + u;
    if (n < N) Wt[(size_t)n * K + k0 + tx] = f2b(t[tx][ty + u]);
  }
}

// ---------------- merged per-layer transposes (all dims %32==0, no bounds) ----------------
__global__ __launch_bounds__(256) void transpose4(const float* __restrict__ wq,
                                                  const float* __restrict__ wo,
                                                  const float* __restrict__ w1,
                                                  const float* __restrict__ w2,
                                                  ushort* __restrict__ tq,
                                                  ushort* __restrict__ to,
                                                  ushort* __restrict__ t1,
                                                  ushort* __restrict__ t2) {
  int bid = blockIdx.x;
  const float* W; ushort* Wt; int K, N, xt;
  if (bid < 1728)      {             W = wq; Wt = tq; K = 768;  N = 2304; xt = 72; }
  else if (bid < 2304) { bid -= 1728; W = wo; Wt = to; K = 768;  N = 768;  xt = 24; }
  else if (bid < 4608) { bid -= 2304; W = w1; Wt = t1; K = 768;  N = 3072; xt = 96; }
  else                 { bid -= 4608; W = w2; Wt = t2; K = 3072; N = 768;  xt = 24; }
  int n0 = (bid % xt) * 32, k0 = (bid / xt) * 32;
  __shared__ float t[32][33];
  int tx = threadIdx.x, ty = threadIdx.y;   // 32 x 8
#pragma unroll
  for (int u = 0; u < 32; u += 8)
    t[ty + u][tx] = W[(size_t)(k0 + ty + u) * N + n0 + tx];
  __syncthreads();
#pragma unroll
  for (int u = 0; u < 32; u += 8)
    Wt[(size_t)(n0 + ty + u) * K + k0 + tx] = f2b(t[tx][ty + u]);
}

// ================= bf16 MFMA GEMM v4: BK=32, 3-stage counted-vmcnt =================
// A [M][K] bf16, Bt [N][K] bf16 row-major. K % 32 == 0, N % 128 == 0. Tile 128x128.
// 256 thr / 4 waves (2x2), wave 64x64 = 4x4 frags of 16x16x32, swapped operands
// (lane holds 4 contiguous output cols). 3 LDS buffers (48 KB -> 3 blocks/CU);
// per iter: issue stage(t+2) [4 loads], compute buf t%3, wait vmcnt(4) [t+1
// landed, t+2 in flight], barrier. Round-2 proven 0-conflict swizzle:
// slot g holds global chunk g^((row>>1)&3), same XOR on ds_read (rule #21).
template<int EP, int RESID, int OBF>
__global__ __launch_bounds__(256) void gemm_v4(const ushort* __restrict__ A,
                                               const ushort* __restrict__ Bt,
                                               const float* __restrict__ bias,
                                               const float* __restrict__ resid,
                                               void* __restrict__ Cv,
                                               int M, int N, int K) {
  __shared__ ushort smem[3 * 8192];         // 3 bufs x (As 4096 + Bs 4096) elems

  const int tid = threadIdx.x;
  const int w = tid >> 6, l = tid & 63;
  const int fr = l & 15, fc = l >> 4;

  // bijective XCD-aware swizzle (m204)
  const int ntx = gridDim.x;
  const int nwg = ntx * gridDim.y;
  const int orig = blockIdx.y * ntx + blockIdx.x;
  const int q = nwg >> 3, r = nwg & 7, xcd = orig & 7, idx = orig >> 3;
  const int wg = (xcd < r ? xcd * (q + 1) : r * (q + 1) + (xcd - r) * q) + idx;
  const int row0 = (wg / ntx) * 128, col0 = (wg % ntx) * 128;

  const int wr = (w >> 1) * 64, wc = (w & 1) * 64;

  // staging: chunks c0=tid, c1=tid+256; row=c>>2, slot g=c&3 holds global
  // chunk g^((row>>1)&3). (row+64)>>1 ≡ row>>1 mod 4 -> same gs for c1.
  const int srow = tid >> 2;
  const int sg = (tid & 3) ^ ((srow >> 1) & 3);
  const ushort* pA0 = A  + (size_t)(row0 + srow) * K + sg * 8;
  const ushort* pA1 = A  + (size_t)(row0 + 64 + srow) * K + sg * 8;
  const ushort* pB0 = Bt + (size_t)(col0 + srow) * K + sg * 8;
  const ushort* pB1 = Bt + (size_t)(col0 + 64 + srow) * K + sg * 8;

  auto stage = [&](int t_, int bi_) {
    ushort* dst = smem + bi_ * 8192;
    const int k0 = t_ * 32;
    gload16(pA0 + k0, dst + tid * 8);
    gload16(pA1 + k0, dst + (tid + 256) * 8);
    gload16(pB0 + k0, dst + 4096 + tid * 8);
    gload16(pB1 + k0, dst + 4096 + (tid + 256) * 8);
  };

  // frag read offsets (elems within an As/Bs buf), constant per thread
  int idxA[4], idxB[4];
#pragma unroll
  for (int m = 0; m < 4; ++m) {
    int rA = wr + m * 16 + fr;
    idxA[m] = rA * 32 + ((fc ^ ((rA >> 1) & 3)) << 3);
  }
#pragma unroll
  for (int n = 0; n < 4; ++n) {
    int rB = wc + n * 16 + fr;
    idxB[n] = rB * 32 + ((fc ^ ((rB >> 1) & 3)) << 3);
  }

  f32x4 acc[4][4] = {};
  const int NT = K >> 5;

  // prologue: 2 stages in flight, wait for the first
  stage(0, 0);
  stage(1, 1);
  asm volatile("s_waitcnt vmcnt(4)" ::: "memory");
  __builtin_amdgcn_s_barrier();

  int bi = 0, si = 2;
  for (int t = 0; t < NT; ++t) {
    const bool more2 = (t + 2 < NT);
    if (more2) stage(t + 2, si);
    const ushort* As = smem + bi * 8192;
    const ushort* Bs = As + 4096;
    bf16x8 a_[4], b_[4];
#pragma unroll
    for (int m = 0; m < 4; ++m) a_[m] = *(const bf16x8*)(As + idxA[m]);
#pragma unroll
    for (int n = 0; n < 4; ++n) b_[n] = *(const bf16x8*)(Bs + idxB[n]);
#pragma unroll
    for (int m = 0; m < 4; ++m)
#pragma unroll
      for (int n = 0; n < 4; ++n)
        acc[m][n] = __builtin_amdgcn_mfma_f32_16x16x32_bf16(b_[n], a_[m], acc[m][n], 0, 0, 0);
    if (t + 1 < NT) {
      if (more2) asm volatile("s_waitcnt vmcnt(4)" ::: "memory");
      else       asm volatile("s_waitcnt vmcnt(0)" ::: "memory");
      __builtin_amdgcn_s_barrier();
    }
    bi = (bi == 2) ? 0 : bi + 1;
    si = (si == 2) ? 0 : si + 1;
  }

  if (!OBF) {
    // fp32 output: dwordx4 bias/resid/store (64B row segments)
    float* Cf = (float*)Cv;
#pragma unroll
    for (int m = 0; m < 4; ++m) {
      int row = row0 + wr + m * 16 + fr;
      if (row >= M) continue;
#pragma unroll
      for (int n = 0; n < 4; ++n) {
        int col = col0 + wc + n * 16 + fc * 4;
        f32x4 v = acc[m][n];
        if (bias) v += *(const f32x4*)(bias + col);
        if (EP) {
#pragma unroll
          for (int rr = 0; rr < 4; ++rr) v[rr] = gelu_f(v[rr]);
        }
        if (RESID) v += *(const f32x4*)(resid + (size_t)row * N + col);
        *(f32x4*)(Cf + (size_t)row * N + col) = v;
      }
    }
  } else {
    // bf16 output: per-wave LDS restage -> ushort4 stores (128B rows)
    __syncthreads();                       // all waves done with K-loop LDS reads
    ushort* Cw = smem + w * 4096;
#pragma unroll
    for (int m = 0; m < 4; ++m) {
      int rl = m * 16 + fr;
#pragma unroll
      for (int n = 0; n < 4; ++n) {
        int col = col0 + wc + n * 16 + fc * 4;
        f32x4 v = acc[m][n];
        if (bias) v += *(const f32x4*)(bias + col);
        if (EP) {
#pragma unroll
          for (int rr = 0; rr < 4; ++rr) v[rr] = gelu_f(v[rr]);
        }
        u16x4 pk = { f2b(v[0]), f2b(v[1]), f2b(v[2]), f2b(v[3]) };
        int s = (n * 4 + fc) ^ (rl & 7);
        *(u16x4*)(Cw + rl * 64 + s * 4) = pk;
      }
    }
    ushort* Cb = (ushort*)Cv;
#pragma unroll
    for (int pp = 0; pp < 16; ++pp) {
      int rl = pp * 4 + (l >> 4);
      int cs = l & 15;
      u16x4 pk = *(const u16x4*)(Cw + rl * 64 + ((cs ^ (rl & 7)) * 4));
      int row = row0 + wr + rl;
      if (row < M) *(u16x4*)(Cb + (size_t)row * N + col0 + wc + cs * 4) = pk;
    }
  }
}

// ---------------- 128x128 bf16 MFMA GEMM (head only, N-bounds-safe) ----------------
template<int EP, int RESID, int OBF>
__global__ __launch_bounds__(256) void gemm_bt(const ushort* __restrict__ A,
                                               const ushort* __restrict__ Bt,
                                               const float* __restrict__ bias,
                                               const float* __restrict__ resid,
                                               void* __restrict__ C,
                                               int M, int N, int K) {
  __shared__ ushort As[128 * 32];
  __shared__ ushort Bs[128 * 32];
  int tid = threadIdx.x;
  int w = tid >> 6, l = tid & 63;
  int fr = l & 15, fc = l >> 4;
  int row0 = blockIdx.y * 128, col0 = blockIdx.x * 128;
  int wr = (w >> 1) * 64, wc = (w & 1) * 64;

  int srow0 = w * 32 + (l >> 2);
  int srow1 = srow0 + 16;
  int sc0 = (((l & 3) ^ ((srow0 >> 1) & 3)) << 3);
  int sc1 = (((l & 3) ^ ((srow1 >> 1) & 3)) << 3);
  const ushort* ga0 = A  + (size_t)(row0 + srow0) * K + sc0;
  const ushort* ga1 = A  + (size_t)(row0 + srow1) * K + sc1;
  const ushort* gb0 = Bt + (size_t)(col0 + srow0) * K + sc0;
  const ushort* gb1 = Bt + (size_t)(col0 + srow1) * K + sc1;

  int idxA[4], idxB[4];
#pragma unroll
  for (int m = 0; m < 4; ++m) {
    int rA = wr + m * 16 + fr;
    idxA[m] = rA * 32 + ((fc ^ ((rA >> 1) & 3)) << 3);
  }
#pragma unroll
  for (int n = 0; n < 4; ++n) {
    int rB = wc + n * 16 + fr;
    idxB[n] = rB * 32 + ((fc ^ ((rB >> 1) & 3)) << 3);
  }

  f32x4 acc[4][4] = {};

  for (int k0 = 0; k0 < K; k0 += 32) {
    gload16(ga0 + k0, &As[w * 1024]);
    gload16(ga1 + k0, &As[w * 1024 + 512]);
    gload16(gb0 + k0, &Bs[w * 1024]);
    gload16(gb1 + k0, &Bs[w * 1024 + 512]);
    __syncthreads();
    bf16x8 af[4], bfr[4];
#pragma unroll
    for (int m = 0; m < 4; ++m) af[m] = *(const bf16x8*)(As + idxA[m]);
#pragma unroll
    for (int n = 0; n < 4; ++n) bfr[n] = *(const bf16x8*)(Bs + idxB[n]);
#pragma unroll
    for (int m = 0; m < 4; ++m)
#pragma unroll
      for (int n = 0; n < 4; ++n)
        acc[m][n] = __builtin_amdgcn_mfma_f32_16x16x32_bf16(af[m], bfr[n], acc[m][n], 0, 0, 0);
    __syncthreads();
  }

#pragma unroll
  for (int n = 0; n < 4; ++n) {
    int col = col0 + wc + n * 16 + fr;
    if (col >= N) continue;
    float bv = bias ? bias[col] : 0.f;
#pragma unroll
    for (int m = 0; m < 4; ++m) {
#pragma unroll
      for (int rr = 0; rr < 4; ++rr) {
        int row = row0 + wr + m * 16 + fc * 4 + rr;
        if (row >= M) continue;
        float v = acc[m][n][rr] + bv;
        if (EP == 1) v = 0.5f * v * (1.0f + erff(v * 0.70710678118654752f));
        if (RESID) v += resid[(size_t)row * N + col];
        if (OBF) ((ushort*)C)[(size_t)row * N + col] = f2b(v);
        else     ((float*)C)[(size_t)row * N + col]  = v;
      }
    }
  }
}

// ---------------- MFMA flash attention ----------------
__global__ __launch_bounds__(256) void attn_mfma(const ushort* __restrict__ qkv,
                                                 ushort* __restrict__ aout) {
  int bid = blockIdx.x;
  int qt = bid & 3;
  int h  = (bid >> 2) % NH;
  int b  = (bid >> 2) / NH;
  int tid = threadIdx.x, w = tid >> 6, l = tid & 63;
  int fr = l & 15, fc = l >> 4;

  __shared__ ushort Vt[64 * 64];        // swizzled V^T tile [d][key]
  __shared__ ushort Pl[4 * 16 * 64];    // per-wave P [qrow][key], swizzled

  const size_t brow = (size_t)b * NTOK;
  int q0 = qt * 64 + w * 16;

  bf16x8 qf[2];
  {
    const ushort* qp = qkv + (brow + q0 + fr) * 2304 + h * 64 + fc * 8;
    qf[0] = *(const bf16x8*)qp;
    qf[1] = *(const bf16x8*)(qp + 32);
  }
  float rs[4] = {0.f, 0.f, 0.f, 0.f};
  f32x4 oc[4] = {};

  for (int kt = 0; kt < 4; ++kt) {
    __syncthreads();
    {
      int key = tid >> 2, d0 = (tid & 3) * 16;
      int j = kt * 64 + key;
      bool valid = j < NTOK;
      const ushort* vp = qkv + (brow + j) * 2304 + 1536 + h * 64 + d0;
      ushort vbuf[16];
      if (valid) {
        *(bf16x8*)(vbuf)     = *(const bf16x8*)vp;
        *(bf16x8*)(vbuf + 8) = *(const bf16x8*)(vp + 8);
      } else {
#pragma unroll
        for (int i = 0; i < 16; ++i) vbuf[i] = 0;
      }
#pragma unroll
      for (int i = 0; i < 16; ++i) {
        int d = d0 + i;
        int byte = d * 128 + ((((key >> 3)) ^ (d & 7)) << 4) + (key & 7) * 2;
        Vt[byte >> 1] = vbuf[i];
      }
    }
    f32x4 sc[4];
#pragma unroll
    for (int n = 0; n < 4; ++n) {
      f32x4 z = {};
      const ushort* kp = qkv + (brow + kt * 64 + n * 16 + fr) * 2304 + 768 + h * 64 + fc * 8;
      bf16x8 k0 = *(const bf16x8*)kp;
      bf16x8 k1 = *(const bf16x8*)(kp + 32);
      z = __builtin_amdgcn_mfma_f32_16x16x32_bf16(qf[0], k0, z, 0, 0, 0);
      z = __builtin_amdgcn_mfma_f32_16x16x32_bf16(qf[1], k1, z, 0, 0, 0);
      sc[n] = z;
    }
    float part[4] = {0.f, 0.f, 0.f, 0.f};
#pragma unroll
    for (int n = 0; n < 4; ++n) {
      int j = kt * 64 + n * 16 + fr;
      bool jv = j < NTOK;
#pragma unroll
      for (int rr = 0; rr < 4; ++rr) {
        float e = jv ? __expf(sc[n][rr] * 0.125f) : 0.f;
        part[rr] += e;
        int row = fc * 4 + rr, col = n * 16 + fr;
        int byte = row * 128 + (((col >> 3) ^ (row & 7)) << 4) + (col & 7) * 2;
        Pl[w * 1024 + (byte >> 1)] = f2b(e);
      }
    }
#pragma unroll
    for (int rr = 0; rr < 4; ++rr) {
      float p = part[rr];
      p += __shfl_xor(p, 1); p += __shfl_xor(p, 2);
      p += __shfl_xor(p, 4); p += __shfl_xor(p, 8);
      rs[rr] += p;
    }
    __syncthreads();
#pragma unroll
    for (int ks = 0; ks < 2; ++ks) {
      int prow = fr;
      int pbyte = prow * 128 + (((ks * 4 + fc) ^ (prow & 7)) << 4);
      bf16x8 pf = *(const bf16x8*)(Pl + w * 1024 + (pbyte >> 1));
#pragma unroll
      for (int n = 0; n < 4; ++n) {
        int d = n * 16 + fr;
        int vb = d * 128 + (((ks * 4 + fc) ^ (d & 7)) << 4);
        bf16x8 vf = *(const bf16x8*)(Vt + (vb >> 1));
        oc[n] = __builtin_amdgcn_mfma_f32_16x16x32_bf16(pf, vf, oc[n], 0, 0, 0);
      }
    }
  }
#pragma unroll
  for (int n = 0; n < 4; ++n) {
#pragma unroll
    for (int rr = 0; rr < 4; ++rr) {
      int qq = q0 + fc * 4 + rr;
      if (qq < NTOK) {
        float v = oc[n][rr] / (rs[rr] + 1e-8f);
        aout[(brow + qq) * 768 + h * 64 + n * 16 + fr] = f2b(v);
      }
    }
  }
}

// ---------------- host launch ----------------
extern "C" void kernel_launch(void* const* d_in, const int* in_sizes, int n_in,
                              void* d_out, int out_size, void* d_ws, size_t ws_size,
                              hipStream_t stream) {
  const float* img       = (const float*)d_in[0];
  const float* p_ln1_g   = (const float*)d_in[1];
  const float* p_ln1_b   = (const float*)d_in[2];
  const float* patch_w   = (const float*)d_in[3];
  const float* patch_b   = (const float*)d_in[4];
  const float* p_ln2_g   = (const float*)d_in[5];
  const float* p_ln2_b   = (const float*)d_in[6];
  const float* pos_emb   = (const float*)d_in[7];
  const float* cls_tok   = (const float*)d_in[8];
  const float* attn_ln_g = (const float*)d_in[9];
  const float* attn_ln_b = (const float*)d_in[10];
  const float* w_qkv     = (const float*)d_in[11];
  const float* w_out     = (const float*)d_in[12];
  const float* b_out     = (const float*)d_in[13];
  const float* ff_ln_g   = (const float*)d_in[14];
  const float* ff_ln_b   = (const float*)d_in[15];
  const float* ff_w1     = (const float*)d_in[16];
  const float* ff_b1     = (const float*)d_in[17];
  const float* ff_w2     = (const float*)d_in[18];
  const float* ff_b2     = (const float*)d_in[19];
  const float* fin_ln_g  = (const float*)d_in[20];
  const float* fin_ln_b  = (const float*)d_in[21];
  const float* head_w    = (const float*)d_in[22];
  const float* head_b    = (const float*)d_in[23];
  float* out = (float*)d_out;

  // ---- workspace carve ----
  char* p = (char*)d_ws;
  auto alloc = [&](size_t bytes) { char* r = p; p += (bytes + 255) & ~(size_t)255; return r; };
  float*  x      = (float*) alloc((size_t)ROWS_PAD * 768 * 4);
  ushort* xnb    = (ushort*)alloc((size_t)ROWS_PAD * 768 * 2);
  ushort* qkvb   = (ushort*)alloc((size_t)ROWS_PAD * 2304 * 2);
  ushort* aoutb  = (ushort*)alloc((size_t)ROWS_PAD * 768 * 2);
  ushort* wtq    = (ushort*)alloc((size_t)2304 * 768 * 2);
  ushort* wto    = (ushort*)alloc((size_t)768 * 768 * 2);
  ushort* wt1    = (ushort*)alloc((size_t)3072 * 768 * 2);
  ushort* wt2    = (ushort*)alloc((size_t)768 * 3072 * 2);
  ushort* pwt    = (ushort*)alloc((size_t)768 * 768 * 2);
  ushort* hwt    = (ushort*)alloc((size_t)1024 * 768 * 2);
  ushort* xclsb  = (ushort*)alloc((size_t)128 * 768 * 2);
  ushort* hidb   = qkvb;                 // [ROWS_PAD][3072] aliases qkvb+aoutb
  ushort* xpb    = xnb;                  // patch LN1 out (12544 rows)
  float*  xe     = (float*)qkvb;         // patch GEMM out fp32 (pre-loop only)

  dim3 blk(256), tblk(32, 8);

  // ---- patch embedding ----
  transpose_cast<<<dim3(24, 24), tblk, 0, stream>>>(patch_w, pwt, 768, 768);
  transpose_cast<<<dim3(32, 24), tblk, 0, stream>>>(head_w, hwt, 768, 1000);
  patch_ln1<<<PROWS, blk, 0, stream>>>(img, p_ln1_g, p_ln1_b, xpb);
  gemm_v4<0, 0, 0><<<dim3(6, 98), blk, 0, stream>>>(xpb, pwt, patch_b, nullptr, xe,
                                                    PROWS, 768, 768);
  ln2_pos<<<PROWS, blk, 0, stream>>>(xe, p_ln2_g, p_ln2_b, pos_emb, x);
  cls_init<<<B_, blk, 0, stream>>>(cls_tok, pos_emb, x);

  for (int l = 0; l < NL; ++l) {
    transpose4<<<6912, tblk, 0, stream>>>(w_qkv + (size_t)l * 768 * 2304,
                                          w_out + (size_t)l * 768 * 768,
                                          ff_w1 + (size_t)l * 768 * MFF,
                                          ff_w2 + (size_t)l * MFF * 768,
                                          wtq, wto, wt1, wt2);

    ln_rows_b<<<ROWS, blk, 0, stream>>>(x, 768, attn_ln_g + (size_t)l * 768,
                                        attn_ln_b + (size_t)l * 768, xnb);
    gemm_v4<0, 0, 1><<<dim3(18, 99), blk, 0, stream>>>(xnb, wtq, nullptr, nullptr, qkvb,
                                                       ROWS, 2304, 768);
    attn_mfma<<<B_ * NH * 4, blk, 0, stream>>>(qkvb, aoutb);
    gemm_v4<0, 1, 0><<<dim3(6, 99), blk, 0, stream>>>(aoutb, wto, b_out + (size_t)l * 768,
                                                      x, x, ROWS, 768, 768);
    ln_rows_b<<<ROWS, blk, 0, stream>>>(x, 768, ff_ln_g + (size_t)l * 768,
                                        ff_ln_b + (size_t)l * 768, xnb);
    gemm_v4<1, 0, 1><<<dim3(24, 99), blk, 0, stream>>>(xnb, wt1, ff_b1 + (size_t)l * MFF,
                                                       nullptr, hidb, ROWS, MFF, 768);
    gemm_v4<0, 1, 0><<<dim3(6, 99), blk, 0, stream>>>(hidb, wt2, ff_b2 + (size_t)l * 768,
                                                      x, x, ROWS, 768, MFF);
  }

  // ---- final LN (cls rows) + head ----
  ln_rows_b<<<B_, blk, 0, stream>>>(x, (long)NTOK * 768, fin_ln_g, fin_ln_b, xclsb);
  gemm_bt<0, 0, 0><<<dim3(8, 1), blk, 0, stream>>>(xclsb, hwt, head_b, nullptr, out,
                                                   B_, NCLS, 768);
}